// Round 12
// baseline (819.276 us; speedup 1.0000x reference)
//
#include <hip/hip_runtime.h>

#define N_NODESX 30000
#define M_PAD    30080   // ceil(30000/128)*128
#define N_EDGES0 300000
#define N_E      330000
#define N_GRAPHSX 64
#define N_CLASSESX 100
#define F_XDX 78
#define HEADSX 10
#define HIDX 780
#define N_PAD 896        // ceil(780/128)*128
#define IN_CHX 300
#define KP_GCN 800   // ceil(780/32)*32
#define KH 96        // per-head K pad: ceil(78/32)*32
#define NXCD 8
#define NSL 8        // pooling node-slices per graph

typedef __attribute__((ext_vector_type(8))) short short8v;
typedef __attribute__((ext_vector_type(8))) unsigned short ushort8v;
typedef __attribute__((ext_vector_type(4))) float f32x4;

// ---------- bf16 split helpers ----------
__device__ inline unsigned short f2bf_rne(float f) {
  unsigned u = __float_as_uint(f);
  unsigned r = (u + 0x7FFFu + ((u >> 16) & 1u)) >> 16;
  return (unsigned short)r;
}
__device__ inline float bf2f(unsigned short h) {
  return __uint_as_float(((unsigned)h) << 16);
}
__device__ inline void splitbf(float v, unsigned short& h, unsigned short& l) {
  unsigned short hh = f2bf_rne(v);
  h = hh;
  l = f2bf_rne(v - bf2f(hh));
}
__device__ inline unsigned packbf(float v) {
  unsigned short hh, ll;
  splitbf(v, hh, ll);
  return ((unsigned)hh << 16) | (unsigned)ll;
}
__device__ inline float unpackbf(unsigned u) {
  return __uint_as_float(u & 0xFFFF0000u) + __uint_as_float(u << 16);
}

// ---------- split + transpose: W (K x N) -> planes (Npad x Kp, zero pad) ----------
__global__ void k_splitT(const float* __restrict__ W, int K, int N, int Npad, int Kp,
                         unsigned short* __restrict__ Th, unsigned short* __restrict__ Tl) {
  int idx = blockIdx.x * 256 + threadIdx.x;
  int packs = Kp >> 3;
  if (idx >= Npad * packs) return;
  int n = idx / packs, p = idx - n * packs;
  ushort8v h, l;
  #pragma unroll
  for (int j = 0; j < 8; j++) {
    int k = p * 8 + j;
    float v = (n < N && k < K) ? W[(size_t)k * N + n] : 0.f;
    unsigned short hh, ll;
    splitbf(v, hh, ll);
    h[j] = hh; l[j] = ll;
  }
  *(ushort8v*)&Th[(size_t)n * Kp + p * 8] = h;
  *(ushort8v*)&Tl[(size_t)n * Kp + p * 8] = l;
}

// ---------- per-head W_gat planes: [10][128][KH] hi/lo ----------
__global__ void k_splitT_heads(const float* __restrict__ W,
                               unsigned short* __restrict__ Th, unsigned short* __restrict__ Tl) {
  int idx = blockIdx.x * 256 + threadIdx.x;
  const int packs = KH >> 3;                           // 12
  if (idx >= HEADSX * 128 * packs) return;
  int hd = idx / (128 * packs);
  int rem = idx - hd * 128 * packs;
  int n = rem / packs, p = rem - n * packs;
  ushort8v h, l;
  #pragma unroll
  for (int j = 0; j < 8; j++) {
    int k = p * 8 + j;
    float v = (n < F_XDX && k < F_XDX) ? W[(size_t)k * HIDX + hd * F_XDX + n] : 0.f;
    unsigned short hh, ll;
    splitbf(v, hh, ll);
    h[j] = hh; l[j] = ll;
  }
  size_t o = ((size_t)hd * 128 + n) * KH + p * 8;
  *(ushort8v*)&Th[o] = h;
  *(ushort8v*)&Tl[o] = l;
}

// ---------- attention weight fold ----------
__global__ void k_wal(const float* __restrict__ W, const float* __restrict__ a_src,
                      const float* __restrict__ a_dst,
                      float* __restrict__ w_as, float* __restrict__ w_ad) {
  int idx = blockIdx.x * 256 + threadIdx.x;
  if (idx >= HEADSX * F_XDX) return;
  int hd = idx / F_XDX, k = idx - hd * F_XDX;
  const float* wr = W + (size_t)k * HIDX + hd * F_XDX;
  const float* as = a_src + hd * F_XDX;
  const float* ad = a_dst + hd * F_XDX;
  float s1 = 0.f, s2 = 0.f;
  for (int c = 0; c < F_XDX; c++) { float w = wr[c]; s1 += w * as[c]; s2 += w * ad[c]; }
  w_as[idx] = s1; w_ad[idx] = s2;
}

// ---------- attention logits ----------
__global__ void k_al2(const float* __restrict__ x, const float* __restrict__ w_as,
                      const float* __restrict__ w_ad,
                      float* __restrict__ al_s, float* __restrict__ al_d) {
  int idx = blockIdx.x * 256 + threadIdx.x;
  if (idx >= N_NODESX * HEADSX) return;
  int n = idx / HEADSX, hd = idx - n * HEADSX;
  const float2* xr = (const float2*)(x + (size_t)n * F_XDX);
  const float2* ws = (const float2*)(w_as + hd * F_XDX);
  const float2* wd = (const float2*)(w_ad + hd * F_XDX);
  float s1 = 0.f, s2 = 0.f;
  #pragma unroll 13
  for (int i = 0; i < F_XDX / 2; i++) {
    float2 v = xr[i], a = ws[i], d = wd[i];
    s1 += v.x * a.x + v.y * a.y;
    s2 += v.x * d.x + v.y * d.y;
  }
  al_s[idx] = s1; al_d[idx] = s2;
}

// ---------- MFMA split-bf16 GEMM (GCN), tile 128x64, BK=32, 48KB LDS dbuf ----------
// 3 blocks/CU (vs 2 at 128x128/64KB) -> better barrier-stall hiding.
// LDS per buf (ushorts): [Ah 4096][Al 4096][Bh 2048][Bl 2048] = 12288 (24KB)
__global__ __launch_bounds__(256)
void gemm_mfma3(const unsigned short* __restrict__ Ah, const unsigned short* __restrict__ Al,
                const unsigned short* __restrict__ Bh, const unsigned short* __restrict__ Bl,
                unsigned* __restrict__ C, int M, int N, int Kp) {
  __shared__ unsigned short lds[2 * 12288];
  const int tid  = threadIdx.x;
  const int lane = tid & 63;
  const int w    = tid >> 6;
  const int wr   = w >> 1, wc = w & 1;

  // bijective XCD-chunk swizzle (m204); col-tile fastest -> A panel L2-resident
  const int nwg = gridDim.x * gridDim.y;
  const int L   = blockIdx.y * gridDim.x + blockIdx.x;
  const int qq = nwg / NXCD, rr8 = nwg % NXCD;
  const int xcd = L % NXCD, pos = L / NXCD;
  const int newL = (xcd < rr8 ? xcd * (qq + 1) : rr8 * (qq + 1) + (xcd - rr8) * qq) + pos;
  const int bm = (newL / gridDim.x) * 128;
  const int bn = (newL % gridDim.x) * 64;

  f32x4 acc[4][2];
  #pragma unroll
  for (int m = 0; m < 4; m++)
    #pragma unroll
    for (int n = 0; n < 2; n++) acc[m][n] = (f32x4){0.f, 0.f, 0.f, 0.f};

  // stage one 32-wide K-tile: 1536 packets of 16B (A:1024, B:512), 6/thread.
  // dest packet = i*256 + w*64 + lane (wave-uniform base + lane*16 = HW rule).
#define STAGE(buf, k0)                                                         \
  {                                                                            \
    _Pragma("unroll")                                                          \
    for (int i = 0; i < 6; i++) {                                              \
      const int p = i * 256 + tid;                                             \
      const int q6 = p & 63;                                                   \
      const int ks = q6 >> 4, r16 = q6 & 15;                                   \
      const unsigned short* gsrc;                                              \
      if (p < 1024) {                                                          \
        const int fm = (p & 511) >> 6;                                         \
        const int row = bm + fm * 16 + r16;                                    \
        gsrc = ((p >> 9) ? Al : Ah) + (size_t)row * Kp + (k0) + ks * 8;        \
      } else {                                                                 \
        const int pb = p - 1024;                                               \
        const int fn = (pb & 255) >> 6;                                        \
        const int row = bn + fn * 16 + r16;                                    \
        gsrc = ((pb >> 8) ? Bl : Bh) + (size_t)row * Kp + (k0) + ks * 8;       \
      }                                                                        \
      unsigned short* lp = (unsigned short*)lds + (buf) * 12288                \
                           + (i * 256 + (w << 6)) * 8;                         \
      __builtin_amdgcn_global_load_lds(                                        \
          (const __attribute__((address_space(1))) unsigned int*)gsrc,         \
          (__attribute__((address_space(3))) unsigned int*)lp, 16, 0, 0);      \
    }                                                                          \
  }

  const int nt = Kp >> 5;
  STAGE(0, 0);
  __syncthreads();
  int cur = 0;
  for (int t = 0; t < nt; ++t) {
    if (t + 1 < nt) STAGE(cur ^ 1, (t + 1) << 5);
    const unsigned short* Lb = (const unsigned short*)lds + cur * 12288;
    short8v afh[4], afl[4], bfh[2], bfl[2];
    #pragma unroll
    for (int m = 0; m < 4; m++) {
      int fmA = wr * 4 + m;
      afh[m] = *(const short8v*)&Lb[0    + fmA * 512 + lane * 8];
      afl[m] = *(const short8v*)&Lb[4096 + fmA * 512 + lane * 8];
    }
    #pragma unroll
    for (int n = 0; n < 2; n++) {
      int fnB = wc * 2 + n;
      bfh[n] = *(const short8v*)&Lb[8192  + fnB * 512 + lane * 8];
      bfl[n] = *(const short8v*)&Lb[10240 + fnB * 512 + lane * 8];
    }
    #pragma unroll
    for (int m = 0; m < 4; m++) {
      #pragma unroll
      for (int n = 0; n < 2; n++) {
        acc[m][n] = __builtin_amdgcn_mfma_f32_16x16x32_bf16(afh[m], bfh[n], acc[m][n], 0, 0, 0);
        acc[m][n] = __builtin_amdgcn_mfma_f32_16x16x32_bf16(afh[m], bfl[n], acc[m][n], 0, 0, 0);
        acc[m][n] = __builtin_amdgcn_mfma_f32_16x16x32_bf16(afl[m], bfh[n], acc[m][n], 0, 0, 0);
      }
    }
    __syncthreads();
    cur ^= 1;
  }
#undef STAGE

  // epilogue: C/D layout col = lane&15, row = (lane>>4)*4 + r  [m89-verified]
  const int r0 = (lane >> 4) * 4;
  const int cc = lane & 15;
  #pragma unroll
  for (int m = 0; m < 4; m++) {
    #pragma unroll
    for (int n = 0; n < 2; n++) {
      int gcol = bn + (wc * 2 + n) * 16 + cc;
      if (gcol >= N) continue;
      #pragma unroll
      for (int r2 = 0; r2 < 4; r2++) {
        int grow = bm + (wr * 4 + m) * 16 + r0 + r2;
        if (grow < M) C[(size_t)grow * N + gcol] = packbf(acc[m][n][r2]);
      }
    }
  }
}

// ---------- per-head MFMA GEMM: xg_hd = relu(z_hd @ W_hd + b) -> split planes ----------
__global__ __launch_bounds__(256)
void gemm_head(const unsigned short* __restrict__ Zh, const unsigned short* __restrict__ Zl,
               const unsigned short* __restrict__ Wh, const unsigned short* __restrict__ Wl,
               const float* __restrict__ bias,
               unsigned short* __restrict__ Ch, unsigned short* __restrict__ Cl) {
  __shared__ unsigned short lds[2 * 16384];
  const int tid  = threadIdx.x;
  const int lane = tid & 63;
  const int w    = tid >> 6;
  const int wr   = w >> 1, wc = w & 1;
  const int hd = blockIdx.z;
  const int bm = blockIdx.y * 128;

  const unsigned short* srcs[4] = {
    Zh + (size_t)hd * M_PAD * KH, Zl + (size_t)hd * M_PAD * KH,
    Wh + (size_t)hd * 128 * KH,   Wl + (size_t)hd * 128 * KH };

  f32x4 acc[4][4];
  #pragma unroll
  for (int m = 0; m < 4; m++)
    #pragma unroll
    for (int n = 0; n < 4; n++) acc[m][n] = (f32x4){0.f, 0.f, 0.f, 0.f};

#define STAGEH(buf, k0)                                                        \
  {                                                                            \
    _Pragma("unroll")                                                          \
    for (int i = 0; i < 8; i++) {                                              \
      const int plane = i >> 1;                                                \
      const int qp = ((i & 1) << 8) + tid;                                     \
      const int fm = qp >> 6;                                                  \
      const int ks = (qp & 63) >> 4, r16 = qp & 15;                            \
      const int row = ((plane < 2) ? bm : 0) + fm * 16 + r16;                  \
      const unsigned short* gp = srcs[plane] + (size_t)row * KH + (k0) + ks * 8; \
      unsigned short* lp = (unsigned short*)lds + (buf) * 16384 + plane * 4096 \
                           + (((i & 1) << 8) + (w << 6)) * 8;                  \
      __builtin_amdgcn_global_load_lds(                                        \
          (const __attribute__((address_space(1))) unsigned int*)gp,           \
          (__attribute__((address_space(3))) unsigned int*)lp, 16, 0, 0);      \
    }                                                                          \
  }

  const int nt = KH >> 5;   // 3
  STAGEH(0, 0);
  __syncthreads();
  int cur = 0;
  for (int t = 0; t < nt; ++t) {
    if (t + 1 < nt) STAGEH(cur ^ 1, (t + 1) << 5);
    const unsigned short* Lb = (const unsigned short*)lds + cur * 16384;
    short8v afh[4], afl[4], bfh[4], bfl[4];
    #pragma unroll
    for (int m = 0; m < 4; m++) {
      int fmA = wr * 4 + m;
      afh[m] = *(const short8v*)&Lb[0 * 4096 + fmA * 512 + lane * 8];
      afl[m] = *(const short8v*)&Lb[1 * 4096 + fmA * 512 + lane * 8];
    }
    #pragma unroll
    for (int n = 0; n < 4; n++) {
      int fnB = wc * 4 + n;
      bfh[n] = *(const short8v*)&Lb[2 * 4096 + fnB * 512 + lane * 8];
      bfl[n] = *(const short8v*)&Lb[3 * 4096 + fnB * 512 + lane * 8];
    }
    #pragma unroll
    for (int m = 0; m < 4; m++) {
      #pragma unroll
      for (int n = 0; n < 4; n++) {
        acc[m][n] = __builtin_amdgcn_mfma_f32_16x16x32_bf16(afh[m], bfh[n], acc[m][n], 0, 0, 0);
        acc[m][n] = __builtin_amdgcn_mfma_f32_16x16x32_bf16(afh[m], bfl[n], acc[m][n], 0, 0, 0);
        acc[m][n] = __builtin_amdgcn_mfma_f32_16x16x32_bf16(afl[m], bfh[n], acc[m][n], 0, 0, 0);
      }
    }
    __syncthreads();
    cur ^= 1;
  }
#undef STAGEH

  const int r0 = (lane >> 4) * 4;
  const int cc = lane & 15;
  #pragma unroll
  for (int n = 0; n < 4; n++) {
    int gcol = (wc * 4 + n) * 16 + cc;     // 0..127
    if (gcol >= F_XDX) continue;
    float bb = bias[hd * F_XDX + gcol];
    #pragma unroll
    for (int m = 0; m < 4; m++) {
      #pragma unroll
      for (int r2 = 0; r2 < 4; r2++) {
        int grow = bm + (wr * 4 + m) * 16 + r0 + r2;
        if (grow >= N_NODESX) continue;
        float v = fmaxf(acc[m][n][r2] + bb, 0.f);
        unsigned short hh, ll;
        splitbf(v, hh, ll);
        size_t o = (size_t)grow * KP_GCN + hd * F_XDX + gcol;
        Ch[o] = hh; Cl[o] = ll;
      }
    }
  }
}

// ---------- zero xgh/xgl K-pad cols 780..799 ----------
__global__ void k_zero_xgpad(unsigned short* __restrict__ Ch, unsigned short* __restrict__ Cl) {
  int idx = blockIdx.x * 256 + threadIdx.x;
  if (idx >= M_PAD * 5) return;
  int row = idx / 5, j = idx - row * 5;
  size_t o = (size_t)row * KP_GCN + 780 + j * 4;
  ushort4 z = make_ushort4(0, 0, 0, 0);
  *(ushort4*)&Ch[o] = z;
  *(ushort4*)&Cl[o] = z;
}

// ---------- split-K fp32 GEMM for skinny-M ----------
__global__ __launch_bounds__(256)
void gemm_sk(const float* __restrict__ A, const float* __restrict__ B,
             float* __restrict__ P, int M, int N, int K, int SK) {
  __shared__ float As[16][64];
  __shared__ float Bs[16][64];
  int tid = threadIdx.x;
  int bm = blockIdx.y * 64;
  int bn = blockIdx.x * 64;
  int ks = blockIdx.z * SK;
  int ke = min(K, ks + SK);
  int tr = tid >> 4;
  int tc = tid & 15;
  float acc[4][4] = {{0.f}};
  int la_m = tid >> 2;
  int la_k = (tid & 3) << 2;
  int lb_k4 = (tid >> 6) << 2;
  int lb_n = tid & 63;

  for (int k0 = ks; k0 < ke; k0 += 16) {
    {
      int gm = bm + la_m;
      bool mok = gm < M;
      const float* ap = A + (size_t)gm * K + k0 + la_k;
      #pragma unroll
      for (int q = 0; q < 4; q++) {
        int kk = la_k + q;
        As[kk][la_m] = (mok && (k0 + kk) < ke) ? ap[q] : 0.f;
      }
    }
    {
      int gn = bn + lb_n;
      #pragma unroll
      for (int q = 0; q < 4; q++) {
        int kk = lb_k4 + q;
        int gk = k0 + kk;
        Bs[kk][lb_n] = (gk < ke && gn < N) ? B[(size_t)gk * N + gn] : 0.f;
      }
    }
    __syncthreads();
    #pragma unroll
    for (int kk = 0; kk < 16; kk++) {
      float a0 = As[kk][tr*4+0], a1 = As[kk][tr*4+1],
            a2 = As[kk][tr*4+2], a3 = As[kk][tr*4+3];
      float b0 = Bs[kk][tc*4+0], b1 = Bs[kk][tc*4+1],
            b2 = Bs[kk][tc*4+2], b3 = Bs[kk][tc*4+3];
      acc[0][0] += a0*b0; acc[0][1] += a0*b1; acc[0][2] += a0*b2; acc[0][3] += a0*b3;
      acc[1][0] += a1*b0; acc[1][1] += a1*b1; acc[1][2] += a1*b2; acc[1][3] += a1*b3;
      acc[2][0] += a2*b0; acc[2][1] += a2*b1; acc[2][2] += a2*b2; acc[2][3] += a2*b3;
      acc[3][0] += a3*b0; acc[3][1] += a3*b1; acc[3][2] += a3*b2; acc[3][3] += a3*b3;
    }
    __syncthreads();
  }
  float* Pp = P + (size_t)blockIdx.z * M * N;
  #pragma unroll
  for (int i = 0; i < 4; i++) {
    int gm = bm + tr*4 + i;
    if (gm >= M) continue;
    #pragma unroll
    for (int j = 0; j < 4; j++) {
      int gn = bn + tc*4 + j;
      if (gn >= N) continue;
      Pp[(size_t)gm * N + gn] = acc[i][j];
    }
  }
}

template<int ACT, bool HAS_BIAS>
__global__ void k_sk_reduce(const float* __restrict__ P, const float* __restrict__ bias,
                            float* __restrict__ C, int MN, int N, int nS) {
  int idx = blockIdx.x * 256 + threadIdx.x;
  if (idx >= MN) return;
  float s = 0.f;
  for (int sl = 0; sl < nS; sl++) s += P[(size_t)sl * MN + idx];
  if (HAS_BIAS) s += bias[idx % N];
  if (ACT == 1) s = fmaxf(s, 0.f);
  else if (ACT == 2) s = s > 0.f ? s : 0.2f * s;
  C[idx] = s;
}

// ---------- CSR build ----------
__global__ void k_count(const int* __restrict__ ei, int* __restrict__ counts) {
  int e = blockIdx.x * 256 + threadIdx.x;
  if (e >= N_E) return;
  int dst = (e < N_EDGES0) ? ei[N_EDGES0 + e] : (e - N_EDGES0);
  atomicAdd(&counts[dst], 1);
}

__global__ void k_scan(const int* __restrict__ cnt, int* __restrict__ row_ptr) {
  __shared__ int part[1024];
  int tid = threadIdx.x;
  const int CH = 30;
  int b0 = tid * CH;
  int s = 0;
  for (int i = 0; i < CH; i++) { int g = b0 + i; if (g < N_NODESX) s += cnt[g]; }
  part[tid] = s;
  __syncthreads();
  for (int off = 1; off < 1024; off <<= 1) {
    int v = (tid >= off) ? part[tid - off] : 0;
    __syncthreads();
    part[tid] += v;
    __syncthreads();
  }
  int pre = (tid > 0) ? part[tid - 1] : 0;
  for (int i = 0; i < CH; i++) {
    int g = b0 + i;
    if (g < N_NODESX) { row_ptr[g] = pre; pre += cnt[g]; }
  }
  if (tid == 1023) row_ptr[N_NODESX] = part[1023];
}

__global__ void k_fill(const int* __restrict__ ei, const int* __restrict__ row_ptr,
                       int* __restrict__ cursor, int* __restrict__ csr_src) {
  int e = blockIdx.x * 256 + threadIdx.x;
  if (e >= N_E) return;
  int src, dst;
  if (e < N_EDGES0) { src = ei[e]; dst = ei[N_EDGES0 + e]; }
  else { src = dst = e - N_EDGES0; }
  int pos = row_ptr[dst] + atomicAdd(&cursor[dst], 1);
  csr_src[pos] = src;
}

// ---------- GAT z-aggregation with FUSED edge softmax ----------
__global__ __launch_bounds__(256)
void k_gat_z(const float* __restrict__ x,
             const float* __restrict__ al_s, const float* __restrict__ al_d,
             const int* __restrict__ row_ptr, const int* __restrict__ csr_src,
             unsigned short* __restrict__ zh, unsigned short* __restrict__ zl) {
  int d = blockIdx.x, t = threadIdx.x;
  if (t >= 240) return;
  if (t >= 200) {               // zero K-pad 80..95 for each head
    int t2 = t - 200;           // 0..39
    int hd = t2 >> 2, j = t2 & 3;
    size_t o = ((size_t)hd * M_PAD + d) * KH + 80 + j * 4;
    ushort4 z4 = make_ushort4(0, 0, 0, 0);
    *(ushort4*)&zh[o] = z4;
    *(ushort4*)&zl[o] = z4;
    return;
  }
  int hd = t / 20, ch = t % 20;
  int k0 = ch * 4;
  bool full = (k0 + 2 < F_XDX);
  float ald = al_d[d * HEADSX + hd];
  float a0 = 0.f, a1 = 0.f, a2 = 0.f, a3 = 0.f, den = 0.f;
  int beg = row_ptr[d], end = row_ptr[d + 1];
  for (int j = beg; j < end; j++) {
    int s = csr_src[j];
    float v = al_s[(size_t)s * HEADSX + hd] + ald;
    v = v > 0.f ? v : 0.2f * v;
    float ex = expf(v);
    den += ex;
    const float* xr = x + (size_t)s * F_XDX + k0;
    float2 p0 = *(const float2*)xr;
    a0 += ex * p0.x; a1 += ex * p0.y;
    if (full) {
      float2 p1 = *(const float2*)(xr + 2);
      a2 += ex * p1.x; a3 += ex * p1.y;
    }
  }
  float id = 1.f / (den + 1e-16f);
  ushort4 h4, l4;
  splitbf(a0 * id, h4.x, l4.x);
  splitbf(a1 * id, h4.y, l4.y);
  splitbf(full ? a2 * id : 0.f, h4.z, l4.z);
  splitbf(full ? a3 * id : 0.f, h4.w, l4.w);
  size_t o = ((size_t)hd * M_PAD + d) * KH + k0;
  *(ushort4*)&zh[o] = h4;
  *(ushort4*)&zl[o] = l4;
}

// ---------- degree inv sqrt ----------
__global__ void k_dinv(const int* __restrict__ counts, float* __restrict__ dinv) {
  int n = blockIdx.x * 256 + threadIdx.x;
  if (n < N_NODESX) dinv[n] = rsqrtf(fmaxf((float)counts[n], 1.f));
}

// ---------- GCN aggregation (gather per dst, packed s) ----------
__global__ __launch_bounds__(256)
void k_gcn_agg(const unsigned* __restrict__ s, const float* __restrict__ dinv,
               const int* __restrict__ row_ptr, const int* __restrict__ csr_src,
               const float* __restrict__ b_gcn, float* __restrict__ out) {
  int d = blockIdx.x, t = threadIdx.x;
  if (t >= HIDX / 4) return;
  int c = t * 4;
  float4 acc = {0.f, 0.f, 0.f, 0.f};
  int beg = row_ptr[d], end = row_ptr[d + 1];
  for (int j = beg; j < end; j++) {
    int si = csr_src[j];
    float w = dinv[si];
    uint4 sv = *(const uint4*)(s + (size_t)si * HIDX + c);
    acc.x += w * unpackbf(sv.x); acc.y += w * unpackbf(sv.y);
    acc.z += w * unpackbf(sv.z); acc.w += w * unpackbf(sv.w);
  }
  float dd = dinv[d];
  float4 bb = *(const float4*)(b_gcn + c);
  float4 r;
  r.x = fmaxf(acc.x * dd + bb.x, 0.f);
  r.y = fmaxf(acc.y * dd + bb.y, 0.f);
  r.z = fmaxf(acc.z * dd + bb.z, 0.f);
  r.w = fmaxf(acc.w * dd + bb.w, 0.f);
  *(float4*)(out + (size_t)d * HIDX + c) = r;
}

// ---------- per-graph ranges: boundary detection (batch sorted, NO atomics) ----------
__global__ void k_range_init(int* __restrict__ gstart, int* __restrict__ gend) {
  int g = threadIdx.x;
  if (g < N_GRAPHSX) { gstart[g] = 0; gend[g] = 0; }
}
__global__ void k_ranges(const int* __restrict__ batch, int* __restrict__ gstart,
                         int* __restrict__ gend) {
  int n = blockIdx.x * 256 + threadIdx.x;
  if (n >= N_NODESX) return;
  int b = batch[n];
  if (n == 0) {
    gstart[b] = 0;
  } else {
    int pb = batch[n - 1];
    if (pb != b) { gend[pb] = n; gstart[b] = n; }
  }
  if (n == N_NODESX - 1) gend[b] = N_NODESX;
}

// ---------- pooling stage A ----------
__global__ __launch_bounds__(256)
void k_pool_a(const float* __restrict__ xg2, const int* __restrict__ gstart,
              const int* __restrict__ gend,
              float* __restrict__ pmax, float* __restrict__ psum) {
  int g = blockIdx.x, sl = blockIdx.y, t = threadIdx.x;
  if (t >= HIDX / 4) return;
  int c = t * 4;
  int st = gstart[g], en = gend[g];
  int len = en - st; if (len < 0) len = 0;
  int chunk = (len + NSL - 1) / NSL;
  int s0 = st + sl * chunk;
  int s1 = min(en, s0 + chunk);
  float4 mx = {0.f, 0.f, 0.f, 0.f};
  float4 sm = {0.f, 0.f, 0.f, 0.f};
  for (int n = s0; n < s1; n++) {
    float4 v = *(const float4*)(xg2 + (size_t)n * HIDX + c);
    mx.x = fmaxf(mx.x, v.x); sm.x += v.x;
    mx.y = fmaxf(mx.y, v.y); sm.y += v.y;
    mx.z = fmaxf(mx.z, v.z); sm.z += v.z;
    mx.w = fmaxf(mx.w, v.w); sm.w += v.w;
  }
  size_t o = ((size_t)g * NSL + sl) * HIDX + c;
  *(float4*)(pmax + o) = mx;
  *(float4*)(psum + o) = sm;
}

// ---------- pooling stage B ----------
__global__ __launch_bounds__(256)
void k_pool_b(const float* __restrict__ pmax, const float* __restrict__ psum,
              const int* __restrict__ gstart, const int* __restrict__ gend,
              float* __restrict__ xf) {
  int g = blockIdx.x, t = threadIdx.x;
  if (t >= HIDX / 4) return;
  int c = t * 4;
  float4 mx = {0.f, 0.f, 0.f, 0.f};
  float4 sm = {0.f, 0.f, 0.f, 0.f};
  #pragma unroll
  for (int sl = 0; sl < NSL; sl++) {
    size_t o = ((size_t)g * NSL + sl) * HIDX + c;
    float4 m = *(const float4*)(pmax + o);
    float4 s = *(const float4*)(psum + o);
    mx.x = fmaxf(mx.x, m.x); sm.x += s.x;
    mx.y = fmaxf(mx.y, m.y); sm.y += s.y;
    mx.z = fmaxf(mx.z, m.z); sm.z += s.z;
    mx.w = fmaxf(mx.w, m.w); sm.w += s.w;
  }
  int st = gstart[g], en = gend[g];
  float inv = (en > st) ? 1.f / (float)(en - st) : 0.f;
  float* xr = xf + (size_t)g * (2 * HIDX);
  float4 mean; mean.x = sm.x*inv; mean.y = sm.y*inv; mean.z = sm.z*inv; mean.w = sm.w*inv;
  *(float4*)(xr + c) = mx;
  *(float4*)(xr + HIDX + c) = mean;
}

// ---------- label branch ----------
__global__ void k_dvec(const float* __restrict__ A, float* __restrict__ dvec) {
  int i = blockIdx.x * 64 + threadIdx.x;
  if (i >= N_CLASSESX) return;
  float s = 0.f;
  for (int j = 0; j < N_CLASSESX; j++) s += A[i * N_CLASSESX + j];
  dvec[i] = rsqrtf(s);
}
__global__ void k_adj(const float* __restrict__ A, const float* __restrict__ dvec,
                      float* __restrict__ adj) {
  int idx = blockIdx.x * 256 + threadIdx.x;
  if (idx >= N_CLASSESX * N_CLASSESX) return;
  int i = idx / N_CLASSESX, j = idx % N_CLASSESX;
  adj[idx] = dvec[i] * A[j * N_CLASSESX + i] * dvec[j];
}

// ---------- final out = fc2o @ y^T : one wave per output ----------
__global__ __launch_bounds__(256)
void k_out(const float* __restrict__ xf2, const float* __restrict__ y,
           float* __restrict__ out) {
  int gw = (blockIdx.x * 256 + threadIdx.x) >> 6;
  int lane = threadIdx.x & 63;
  if (gw >= N_GRAPHSX * N_CLASSESX) return;
  int b = gw / N_CLASSESX, c = gw - b * N_CLASSESX;
  const float4* xr = (const float4*)(xf2 + (size_t)b * 1024);
  const float4* yr = (const float4*)(y + (size_t)c * 1024);
  float s = 0.f;
  #pragma unroll
  for (int i = 0; i < 4; i++) {
    float4 xv = xr[lane + i * 64], yv = yr[lane + i * 64];
    s += xv.x*yv.x + xv.y*yv.y + xv.z*yv.z + xv.w*yv.w;
  }
  #pragma unroll
  for (int off = 32; off > 0; off >>= 1) s += __shfl_down(s, off, 64);
  if (lane == 0) out[gw] = s;
}

// =======================================================================
extern "C" void kernel_launch(void* const* d_in, const int* in_sizes, int n_in,
                              void* d_out, int out_size, void* d_ws, size_t ws_size,
                              hipStream_t stream) {
  const float* x     = (const float*)d_in[0];
  const int*   ei    = (const int*)d_in[1];
  const int*   batch = (const int*)d_in[2];
  const float* inp   = (const float*)d_in[3];
  const float* W_gat = (const float*)d_in[4];
  const float* a_src = (const float*)d_in[5];
  const float* a_dst = (const float*)d_in[6];
  const float* b_gat = (const float*)d_in[7];
  const float* W_gcn = (const float*)d_in[8];
  const float* b_gcn = (const float*)d_in[9];
  const float* W_fc1 = (const float*)d_in[10];
  const float* b_fc1 = (const float*)d_in[11];
  const float* W_fc2 = (const float*)d_in[12];
  const float* b_fc2 = (const float*)d_in[13];
  const float* W_gc1 = (const float*)d_in[14];
  const float* W_gc2 = (const float*)d_in[15];
  const float* A     = (const float*)d_in[16];
  float* out = (float*)d_out;

  char* ws = (char*)d_ws;
  size_t off = 0;
  auto alloc = [&](size_t bytes) -> void* {
    void* p = ws + off;
    off = (off + bytes + 255) & ~(size_t)255;
    return p;
  };

  // regionA: zh|zl planes [10][M_PAD][KH] (GAT phase), then s packed (GCN phase)
  char* regionA = (char*)alloc((size_t)10 * M_PAD * KH * 2 * 2);
  unsigned short* zh = (unsigned short*)regionA;
  unsigned short* zl = zh + (size_t)10 * M_PAD * KH;
  unsigned* spk = (unsigned*)regionA;                        // 93.6MB <= 115.5MB
  // regionB: xgh|xgl [M_PAD][800] planes, then xg2 fp32 [30000][780]
  char* regionB = (char*)alloc((size_t)M_PAD * KP_GCN * 2 * 2);
  unsigned short* xgh = (unsigned short*)regionB;
  unsigned short* xgl = xgh + (size_t)M_PAD * KP_GCN;
  float* xg2 = (float*)regionB;                              // 93.6MB <= 96.3MB

  float* al_s   = (float*)alloc(sizeof(float) * N_NODESX * HEADSX);
  float* al_d   = (float*)alloc(sizeof(float) * N_NODESX * HEADSX);
  int* counts   = (int*)alloc(sizeof(int) * N_NODESX);
  int* row_ptr  = (int*)alloc(sizeof(int) * (N_NODESX + 1));
  int* cursor   = (int*)alloc(sizeof(int) * N_NODESX);
  int* csr_src  = (int*)alloc(sizeof(int) * N_E);
  float* dinv   = (float*)alloc(sizeof(float) * N_NODESX);
  int* gstart   = (int*)alloc(sizeof(int) * N_GRAPHSX);
  int* gend     = (int*)alloc(sizeof(int) * N_GRAPHSX);
  float* xf     = (float*)alloc(sizeof(float) * N_GRAPHSX * 2 * HIDX);
  float* fc1o   = (float*)alloc(sizeof(float) * N_GRAPHSX * 1500);
  float* fc2o   = (float*)alloc(sizeof(float) * N_GRAPHSX * 1024);
  float* t1     = (float*)alloc(sizeof(float) * N_CLASSESX * 1024);
  float* adj    = (float*)alloc(sizeof(float) * N_CLASSESX * N_CLASSESX);
  float* dvec   = (float*)alloc(sizeof(float) * N_CLASSESX);
  float* y1     = (float*)alloc(sizeof(float) * N_CLASSESX * 1024);
  float* t2     = (float*)alloc(sizeof(float) * N_CLASSESX * 1024);
  float* ybuf   = (float*)alloc(sizeof(float) * N_CLASSESX * 1024);
  float* Ppart  = (float*)alloc(sizeof(float) * 13 * 64 * 1500);
  unsigned short* wcTh = (unsigned short*)alloc(sizeof(short) * (size_t)N_PAD * KP_GCN);
  unsigned short* wcTl = (unsigned short*)alloc(sizeof(short) * (size_t)N_PAD * KP_GCN);
  unsigned short* whTh = (unsigned short*)alloc(sizeof(short) * HEADSX * 128 * KH);
  unsigned short* whTl = (unsigned short*)alloc(sizeof(short) * HEADSX * 128 * KH);
  float* w_as = (float*)alloc(sizeof(float) * HEADSX * F_XDX);
  float* w_ad = (float*)alloc(sizeof(float) * HEADSX * F_XDX);
  // pooling partials alias Ppart (disjoint lifetimes, 3.19MB <= 4.99MB)
  float* pmax = Ppart;
  float* psum = Ppart + (size_t)N_GRAPHSX * NSL * HIDX;
  (void)ws_size; (void)in_sizes; (void)n_in; (void)out_size;

  hipMemsetAsync(counts, 0, sizeof(int) * N_NODESX, stream);
  hipMemsetAsync(cursor, 0, sizeof(int) * N_NODESX, stream);

  // weight prep
  k_splitT<<<(N_PAD * (KP_GCN/8) + 255) / 256, 256, 0, stream>>>(
      W_gcn, HIDX, HIDX, N_PAD, KP_GCN, wcTh, wcTl);
  k_splitT_heads<<<(HEADSX * 128 * (KH/8) + 255) / 256, 256, 0, stream>>>(W_gat, whTh, whTl);
  k_wal<<<(HEADSX * F_XDX + 255) / 256, 256, 0, stream>>>(W_gat, a_src, a_dst, w_as, w_ad);

  // attention logits directly from x (h never materialized)
  k_al2<<<(N_NODESX * HEADSX + 255) / 256, 256, 0, stream>>>(x, w_as, w_ad, al_s, al_d);
  // CSR
  k_count<<<(N_E + 255) / 256, 256, 0, stream>>>(ei, counts);
  k_scan<<<1, 1024, 0, stream>>>(counts, row_ptr);
  k_fill<<<(N_E + 255) / 256, 256, 0, stream>>>(ei, row_ptr, cursor, csr_src);
  // GAT: fused edge-softmax + x-aggregation into z planes, then per-head GEMM
  k_gat_z<<<N_NODESX, 256, 0, stream>>>(x, al_s, al_d, row_ptr, csr_src, zh, zl);
  gemm_head<<<dim3(1, M_PAD / 128, HEADSX), 256, 0, stream>>>(
      zh, zl, whTh, whTl, b_gat, xgh, xgl);
  k_zero_xgpad<<<(M_PAD * 5 + 255) / 256, 256, 0, stream>>>(xgh, xgl);
  // GCN
  k_dinv<<<(N_NODESX + 255) / 256, 256, 0, stream>>>(counts, dinv);
  gemm_mfma3<<<dim3(N_PAD / 64, M_PAD / 128), 256, 0, stream>>>(
      xgh, xgl, wcTh, wcTl, spk, N_NODESX, HIDX, KP_GCN);
  k_gcn_agg<<<N_NODESX, 256, 0, stream>>>(spk, dinv, row_ptr, csr_src, b_gcn, xg2);
  // pooling (2-stage; ranges via boundary detection, no atomics)
  k_range_init<<<1, 64, 0, stream>>>(gstart, gend);
  k_ranges<<<(N_NODESX + 255) / 256, 256, 0, stream>>>(batch, gstart, gend);
  k_pool_a<<<dim3(N_GRAPHSX, NSL), 256, 0, stream>>>(xg2, gstart, gend, pmax, psum);
  k_pool_b<<<N_GRAPHSX, 256, 0, stream>>>(pmax, psum, gstart, gend, xf);

  // ---- dense head via split-K ----
  gemm_sk<<<dim3(24, 1, 13), 256, 0, stream>>>(xf, W_fc1, Ppart, 64, 1500, 1560, 128);
  k_sk_reduce<1, true><<<(64 * 1500 + 255) / 256, 256, 0, stream>>>(
      Ppart, b_fc1, fc1o, 64 * 1500, 1500, 13);
  gemm_sk<<<dim3(16, 1, 12), 256, 0, stream>>>(fc1o, W_fc2, Ppart, 64, 1024, 1500, 128);
  k_sk_reduce<0, true><<<(64 * 1024 + 255) / 256, 256, 0, stream>>>(
      Ppart, b_fc2, fc2o, 64 * 1024, 1024, 12);

  // ---- label branch ----
  k_dvec<<<(N_CLASSESX + 63) / 64, 64, 0, stream>>>(A, dvec);
  k_adj<<<(N_CLASSESX * N_CLASSESX + 255) / 256, 256, 0, stream>>>(A, dvec, adj);
  gemm_sk<<<dim3(16, 2, 5), 256, 0, stream>>>(inp, W_gc1, Ppart, 100, 1024, 300, 64);
  k_sk_reduce<0, false><<<(100 * 1024 + 255) / 256, 256, 0, stream>>>(
      Ppart, nullptr, t1, 100 * 1024, 1024, 5);
  gemm_sk<<<dim3(16, 2, 4), 256, 0, stream>>>(adj, t1, Ppart, 100, 1024, 100, 32);
  k_sk_reduce<2, false><<<(100 * 1024 + 255) / 256, 256, 0, stream>>>(
      Ppart, nullptr, y1, 100 * 1024, 1024, 4);
  gemm_sk<<<dim3(16, 2, 8), 256, 0, stream>>>(y1, W_gc2, Ppart, 100, 1024, 1024, 128);
  k_sk_reduce<0, false><<<(100 * 1024 + 255) / 256, 256, 0, stream>>>(
      Ppart, nullptr, t2, 100 * 1024, 1024, 8);
  gemm_sk<<<dim3(16, 2, 4), 256, 0, stream>>>(adj, t2, Ppart, 100, 1024, 100, 32);
  k_sk_reduce<0, false><<<(100 * 1024 + 255) / 256, 256, 0, stream>>>(
      Ppart, nullptr, ybuf, 100 * 1024, 1024, 4);

  // out = fc2o @ ybuf^T (wave per output)
  k_out<<<(N_GRAPHSX * N_CLASSESX * 64 + 255) / 256, 256, 0, stream>>>(fc2o, ybuf, out);
}

// Round 13
// 788.659 us; speedup vs baseline: 1.0388x; 1.0388x over previous
//
#include <hip/hip_runtime.h>

#define N_NODESX 30000
#define M_PAD    30080   // ceil(30000/128)*128
#define N_EDGES0 300000
#define N_E      330000
#define N_GRAPHSX 64
#define N_CLASSESX 100
#define F_XDX 78
#define HEADSX 10
#define HIDX 780
#define N_PAD 896        // ceil(780/128)*128
#define IN_CHX 300
#define KP_GCN 800   // ceil(780/32)*32
#define KH 96        // per-head K pad: ceil(78/32)*32
#define NXCD 8
#define NSL 8        // pooling node-slices per graph

typedef __attribute__((ext_vector_type(8))) short short8v;
typedef __attribute__((ext_vector_type(8))) unsigned short ushort8v;
typedef __attribute__((ext_vector_type(4))) float f32x4;

// ---------- bf16 split helpers ----------
__device__ inline unsigned short f2bf_rne(float f) {
  unsigned u = __float_as_uint(f);
  unsigned r = (u + 0x7FFFu + ((u >> 16) & 1u)) >> 16;
  return (unsigned short)r;
}
__device__ inline float bf2f(unsigned short h) {
  return __uint_as_float(((unsigned)h) << 16);
}
__device__ inline void splitbf(float v, unsigned short& h, unsigned short& l) {
  unsigned short hh = f2bf_rne(v);
  h = hh;
  l = f2bf_rne(v - bf2f(hh));
}
__device__ inline unsigned packbf(float v) {
  unsigned short hh, ll;
  splitbf(v, hh, ll);
  return ((unsigned)hh << 16) | (unsigned)ll;
}
__device__ inline float unpackbf(unsigned u) {
  return __uint_as_float(u & 0xFFFF0000u) + __uint_as_float(u << 16);
}

// ---------- split + transpose: W (K x N) -> planes (Npad x Kp, zero pad) ----------
__global__ void k_splitT(const float* __restrict__ W, int K, int N, int Npad, int Kp,
                         unsigned short* __restrict__ Th, unsigned short* __restrict__ Tl) {
  int idx = blockIdx.x * 256 + threadIdx.x;
  int packs = Kp >> 3;
  if (idx >= Npad * packs) return;
  int n = idx / packs, p = idx - n * packs;
  ushort8v h, l;
  #pragma unroll
  for (int j = 0; j < 8; j++) {
    int k = p * 8 + j;
    float v = (n < N && k < K) ? W[(size_t)k * N + n] : 0.f;
    unsigned short hh, ll;
    splitbf(v, hh, ll);
    h[j] = hh; l[j] = ll;
  }
  *(ushort8v*)&Th[(size_t)n * Kp + p * 8] = h;
  *(ushort8v*)&Tl[(size_t)n * Kp + p * 8] = l;
}

// ---------- per-head W_gat planes: [10][128][KH] hi/lo ----------
__global__ void k_splitT_heads(const float* __restrict__ W,
                               unsigned short* __restrict__ Th, unsigned short* __restrict__ Tl) {
  int idx = blockIdx.x * 256 + threadIdx.x;
  const int packs = KH >> 3;                           // 12
  if (idx >= HEADSX * 128 * packs) return;
  int hd = idx / (128 * packs);
  int rem = idx - hd * 128 * packs;
  int n = rem / packs, p = rem - n * packs;
  ushort8v h, l;
  #pragma unroll
  for (int j = 0; j < 8; j++) {
    int k = p * 8 + j;
    float v = (n < F_XDX && k < F_XDX) ? W[(size_t)k * HIDX + hd * F_XDX + n] : 0.f;
    unsigned short hh, ll;
    splitbf(v, hh, ll);
    h[j] = hh; l[j] = ll;
  }
  size_t o = ((size_t)hd * 128 + n) * KH + p * 8;
  *(ushort8v*)&Th[o] = h;
  *(ushort8v*)&Tl[o] = l;
}

// ---------- attention weight fold ----------
__global__ void k_wal(const float* __restrict__ W, const float* __restrict__ a_src,
                      const float* __restrict__ a_dst,
                      float* __restrict__ w_as, float* __restrict__ w_ad) {
  int idx = blockIdx.x * 256 + threadIdx.x;
  if (idx >= HEADSX * F_XDX) return;
  int hd = idx / F_XDX, k = idx - hd * F_XDX;
  const float* wr = W + (size_t)k * HIDX + hd * F_XDX;
  const float* as = a_src + hd * F_XDX;
  const float* ad = a_dst + hd * F_XDX;
  float s1 = 0.f, s2 = 0.f;
  for (int c = 0; c < F_XDX; c++) { float w = wr[c]; s1 += w * as[c]; s2 += w * ad[c]; }
  w_as[idx] = s1; w_ad[idx] = s2;
}

// ---------- attention logits ----------
__global__ void k_al2(const float* __restrict__ x, const float* __restrict__ w_as,
                      const float* __restrict__ w_ad,
                      float* __restrict__ al_s, float* __restrict__ al_d) {
  int idx = blockIdx.x * 256 + threadIdx.x;
  if (idx >= N_NODESX * HEADSX) return;
  int n = idx / HEADSX, hd = idx - n * HEADSX;
  const float2* xr = (const float2*)(x + (size_t)n * F_XDX);
  const float2* ws = (const float2*)(w_as + hd * F_XDX);
  const float2* wd = (const float2*)(w_ad + hd * F_XDX);
  float s1 = 0.f, s2 = 0.f;
  #pragma unroll 13
  for (int i = 0; i < F_XDX / 2; i++) {
    float2 v = xr[i], a = ws[i], d = wd[i];
    s1 += v.x * a.x + v.y * a.y;
    s2 += v.x * d.x + v.y * d.y;
  }
  al_s[idx] = s1; al_d[idx] = s2;
}

// ---------- MFMA split-bf16 GEMM (GCN), tile 128x128x32, 2-phase dbuf + g_l_lds + XCD swizzle ----------
// [R11 proven config: 164 us, 789 TF effective — structural ceiling of 2-phase template]
__global__ __launch_bounds__(256)
void gemm_mfma3(const unsigned short* __restrict__ Ah, const unsigned short* __restrict__ Al,
                const unsigned short* __restrict__ Bh, const unsigned short* __restrict__ Bl,
                unsigned* __restrict__ C, int M, int N, int Kp) {
  __shared__ unsigned short lds[2 * 16384];
  const int tid  = threadIdx.x;
  const int lane = tid & 63;
  const int w    = tid >> 6;
  const int wr   = w >> 1, wc = w & 1;

  const int nwg = gridDim.x * gridDim.y;
  const int L   = blockIdx.y * gridDim.x + blockIdx.x;
  const int qq = nwg / NXCD, rr8 = nwg % NXCD;
  const int xcd = L % NXCD, pos = L / NXCD;
  const int newL = (xcd < rr8 ? xcd * (qq + 1) : rr8 * (qq + 1) + (xcd - rr8) * qq) + pos;
  const int bm = (newL / gridDim.x) * 128;
  const int bn = (newL % gridDim.x) * 128;

  f32x4 acc[4][4];
  #pragma unroll
  for (int m = 0; m < 4; m++)
    #pragma unroll
    for (int n = 0; n < 4; n++) acc[m][n] = (f32x4){0.f, 0.f, 0.f, 0.f};

  const unsigned short* srcs[4] = {Ah, Al, Bh, Bl};

#define STAGE(buf, k0)                                                         \
  {                                                                            \
    _Pragma("unroll")                                                          \
    for (int i = 0; i < 8; i++) {                                              \
      const int plane = i >> 1;                                                \
      const int qp = ((i & 1) << 8) + tid;                                     \
      const int fm = qp >> 6;                                                  \
      const int ks = (qp & 63) >> 4, r16 = qp & 15;                            \
      const int rowbase = (plane < 2) ? bm : bn;                               \
      const int row = rowbase + fm * 16 + r16;                                 \
      const unsigned short* gp = srcs[plane] + (size_t)row * Kp + (k0) + ks * 8; \
      unsigned short* lp = (unsigned short*)lds + (buf) * 16384 + plane * 4096 \
                           + (((i & 1) << 8) + (w << 6)) * 8;                  \
      __builtin_amdgcn_global_load_lds(                                        \
          (const __attribute__((address_space(1))) unsigned int*)gp,           \
          (__attribute__((address_space(3))) unsigned int*)lp, 16, 0, 0);      \
    }                                                                          \
  }

  const int nt = Kp >> 5;
  STAGE(0, 0);
  __syncthreads();
  int cur = 0;
  for (int t = 0; t < nt; ++t) {
    if (t + 1 < nt) STAGE(cur ^ 1, (t + 1) << 5);
    const unsigned short* Lb = (const unsigned short*)lds + cur * 16384;
    short8v afh[4], afl[4], bfh[4], bfl[4];
    #pragma unroll
    for (int m = 0; m < 4; m++) {
      int fmA = wr * 4 + m;
      afh[m] = *(const short8v*)&Lb[0 * 4096 + fmA * 512 + lane * 8];
      afl[m] = *(const short8v*)&Lb[1 * 4096 + fmA * 512 + lane * 8];
    }
    #pragma unroll
    for (int n = 0; n < 4; n++) {
      int fnB = wc * 4 + n;
      bfh[n] = *(const short8v*)&Lb[2 * 4096 + fnB * 512 + lane * 8];
      bfl[n] = *(const short8v*)&Lb[3 * 4096 + fnB * 512 + lane * 8];
    }
    #pragma unroll
    for (int m = 0; m < 4; m++) {
      #pragma unroll
      for (int n = 0; n < 4; n++) {
        acc[m][n] = __builtin_amdgcn_mfma_f32_16x16x32_bf16(afh[m], bfh[n], acc[m][n], 0, 0, 0);
        acc[m][n] = __builtin_amdgcn_mfma_f32_16x16x32_bf16(afh[m], bfl[n], acc[m][n], 0, 0, 0);
        acc[m][n] = __builtin_amdgcn_mfma_f32_16x16x32_bf16(afl[m], bfh[n], acc[m][n], 0, 0, 0);
      }
    }
    __syncthreads();
    cur ^= 1;
  }
#undef STAGE

  // epilogue: C/D layout col = lane&15, row = (lane>>4)*4 + r  [m89-verified]
  const int r0 = (lane >> 4) * 4;
  const int cc = lane & 15;
  #pragma unroll
  for (int m = 0; m < 4; m++) {
    #pragma unroll
    for (int n = 0; n < 4; n++) {
      int gcol = bn + (wc * 4 + n) * 16 + cc;
      if (gcol >= N) continue;
      #pragma unroll
      for (int r2 = 0; r2 < 4; r2++) {
        int grow = bm + (wr * 4 + m) * 16 + r0 + r2;
        if (grow < M) C[(size_t)grow * N + gcol] = packbf(acc[m][n][r2]);
      }
    }
  }
}

// ---------- per-head MFMA GEMM: xg_hd = relu(z_hd @ W_hd + b) -> split planes ----------
__global__ __launch_bounds__(256)
void gemm_head(const unsigned short* __restrict__ Zh, const unsigned short* __restrict__ Zl,
               const unsigned short* __restrict__ Wh, const unsigned short* __restrict__ Wl,
               const float* __restrict__ bias,
               unsigned short* __restrict__ Ch, unsigned short* __restrict__ Cl) {
  __shared__ unsigned short lds[2 * 16384];
  const int tid  = threadIdx.x;
  const int lane = tid & 63;
  const int w    = tid >> 6;
  const int wr   = w >> 1, wc = w & 1;
  const int hd = blockIdx.z;
  const int bm = blockIdx.y * 128;

  const unsigned short* srcs[4] = {
    Zh + (size_t)hd * M_PAD * KH, Zl + (size_t)hd * M_PAD * KH,
    Wh + (size_t)hd * 128 * KH,   Wl + (size_t)hd * 128 * KH };

  f32x4 acc[4][4];
  #pragma unroll
  for (int m = 0; m < 4; m++)
    #pragma unroll
    for (int n = 0; n < 4; n++) acc[m][n] = (f32x4){0.f, 0.f, 0.f, 0.f};

#define STAGEH(buf, k0)                                                        \
  {                                                                            \
    _Pragma("unroll")                                                          \
    for (int i = 0; i < 8; i++) {                                              \
      const int plane = i >> 1;                                                \
      const int qp = ((i & 1) << 8) + tid;                                     \
      const int fm = qp >> 6;                                                  \
      const int ks = (qp & 63) >> 4, r16 = qp & 15;                            \
      const int row = ((plane < 2) ? bm : 0) + fm * 16 + r16;                  \
      const unsigned short* gp = srcs[plane] + (size_t)row * KH + (k0) + ks * 8; \
      unsigned short* lp = (unsigned short*)lds + (buf) * 16384 + plane * 4096 \
                           + (((i & 1) << 8) + (w << 6)) * 8;                  \
      __builtin_amdgcn_global_load_lds(                                        \
          (const __attribute__((address_space(1))) unsigned int*)gp,           \
          (__attribute__((address_space(3))) unsigned int*)lp, 16, 0, 0);      \
    }                                                                          \
  }

  const int nt = KH >> 5;   // 3
  STAGEH(0, 0);
  __syncthreads();
  int cur = 0;
  for (int t = 0; t < nt; ++t) {
    if (t + 1 < nt) STAGEH(cur ^ 1, (t + 1) << 5);
    const unsigned short* Lb = (const unsigned short*)lds + cur * 16384;
    short8v afh[4], afl[4], bfh[4], bfl[4];
    #pragma unroll
    for (int m = 0; m < 4; m++) {
      int fmA = wr * 4 + m;
      afh[m] = *(const short8v*)&Lb[0 * 4096 + fmA * 512 + lane * 8];
      afl[m] = *(const short8v*)&Lb[1 * 4096 + fmA * 512 + lane * 8];
    }
    #pragma unroll
    for (int n = 0; n < 4; n++) {
      int fnB = wc * 4 + n;
      bfh[n] = *(const short8v*)&Lb[2 * 4096 + fnB * 512 + lane * 8];
      bfl[n] = *(const short8v*)&Lb[3 * 4096 + fnB * 512 + lane * 8];
    }
    #pragma unroll
    for (int m = 0; m < 4; m++) {
      #pragma unroll
      for (int n = 0; n < 4; n++) {
        acc[m][n] = __builtin_amdgcn_mfma_f32_16x16x32_bf16(afh[m], bfh[n], acc[m][n], 0, 0, 0);
        acc[m][n] = __builtin_amdgcn_mfma_f32_16x16x32_bf16(afh[m], bfl[n], acc[m][n], 0, 0, 0);
        acc[m][n] = __builtin_amdgcn_mfma_f32_16x16x32_bf16(afl[m], bfh[n], acc[m][n], 0, 0, 0);
      }
    }
    __syncthreads();
    cur ^= 1;
  }
#undef STAGEH

  const int r0 = (lane >> 4) * 4;
  const int cc = lane & 15;
  #pragma unroll
  for (int n = 0; n < 4; n++) {
    int gcol = (wc * 4 + n) * 16 + cc;     // 0..127
    if (gcol >= F_XDX) continue;
    float bb = bias[hd * F_XDX + gcol];
    #pragma unroll
    for (int m = 0; m < 4; m++) {
      #pragma unroll
      for (int r2 = 0; r2 < 4; r2++) {
        int grow = bm + (wr * 4 + m) * 16 + r0 + r2;
        if (grow >= N_NODESX) continue;
        float v = fmaxf(acc[m][n][r2] + bb, 0.f);
        unsigned short hh, ll;
        splitbf(v, hh, ll);
        size_t o = (size_t)grow * KP_GCN + hd * F_XDX + gcol;
        Ch[o] = hh; Cl[o] = ll;
      }
    }
  }
}

// ---------- zero xgh/xgl K-pad cols 780..799 ----------
__global__ void k_zero_xgpad(unsigned short* __restrict__ Ch, unsigned short* __restrict__ Cl) {
  int idx = blockIdx.x * 256 + threadIdx.x;
  if (idx >= M_PAD * 5) return;
  int row = idx / 5, j = idx - row * 5;
  size_t o = (size_t)row * KP_GCN + 780 + j * 4;
  ushort4 z = make_ushort4(0, 0, 0, 0);
  *(ushort4*)&Ch[o] = z;
  *(ushort4*)&Cl[o] = z;
}

// ---------- split-K fp32 GEMM for skinny-M ----------
__global__ __launch_bounds__(256)
void gemm_sk(const float* __restrict__ A, const float* __restrict__ B,
             float* __restrict__ P, int M, int N, int K, int SK) {
  __shared__ float As[16][64];
  __shared__ float Bs[16][64];
  int tid = threadIdx.x;
  int bm = blockIdx.y * 64;
  int bn = blockIdx.x * 64;
  int ks = blockIdx.z * SK;
  int ke = min(K, ks + SK);
  int tr = tid >> 4;
  int tc = tid & 15;
  float acc[4][4] = {{0.f}};
  int la_m = tid >> 2;
  int la_k = (tid & 3) << 2;
  int lb_k4 = (tid >> 6) << 2;
  int lb_n = tid & 63;

  for (int k0 = ks; k0 < ke; k0 += 16) {
    {
      int gm = bm + la_m;
      bool mok = gm < M;
      const float* ap = A + (size_t)gm * K + k0 + la_k;
      #pragma unroll
      for (int q = 0; q < 4; q++) {
        int kk = la_k + q;
        As[kk][la_m] = (mok && (k0 + kk) < ke) ? ap[q] : 0.f;
      }
    }
    {
      int gn = bn + lb_n;
      #pragma unroll
      for (int q = 0; q < 4; q++) {
        int kk = lb_k4 + q;
        int gk = k0 + kk;
        Bs[kk][lb_n] = (gk < ke && gn < N) ? B[(size_t)gk * N + gn] : 0.f;
      }
    }
    __syncthreads();
    #pragma unroll
    for (int kk = 0; kk < 16; kk++) {
      float a0 = As[kk][tr*4+0], a1 = As[kk][tr*4+1],
            a2 = As[kk][tr*4+2], a3 = As[kk][tr*4+3];
      float b0 = Bs[kk][tc*4+0], b1 = Bs[kk][tc*4+1],
            b2 = Bs[kk][tc*4+2], b3 = Bs[kk][tc*4+3];
      acc[0][0] += a0*b0; acc[0][1] += a0*b1; acc[0][2] += a0*b2; acc[0][3] += a0*b3;
      acc[1][0] += a1*b0; acc[1][1] += a1*b1; acc[1][2] += a1*b2; acc[1][3] += a1*b3;
      acc[2][0] += a2*b0; acc[2][1] += a2*b1; acc[2][2] += a2*b2; acc[2][3] += a2*b3;
      acc[3][0] += a3*b0; acc[3][1] += a3*b1; acc[3][2] += a3*b2; acc[3][3] += a3*b3;
    }
    __syncthreads();
  }
  float* Pp = P + (size_t)blockIdx.z * M * N;
  #pragma unroll
  for (int i = 0; i < 4; i++) {
    int gm = bm + tr*4 + i;
    if (gm >= M) continue;
    #pragma unroll
    for (int j = 0; j < 4; j++) {
      int gn = bn + tc*4 + j;
      if (gn >= N) continue;
      Pp[(size_t)gm * N + gn] = acc[i][j];
    }
  }
}

template<int ACT, bool HAS_BIAS>
__global__ void k_sk_reduce(const float* __restrict__ P, const float* __restrict__ bias,
                            float* __restrict__ C, int MN, int N, int nS) {
  int idx = blockIdx.x * 256 + threadIdx.x;
  if (idx >= MN) return;
  float s = 0.f;
  for (int sl = 0; sl < nS; sl++) s += P[(size_t)sl * MN + idx];
  if (HAS_BIAS) s += bias[idx % N];
  if (ACT == 1) s = fmaxf(s, 0.f);
  else if (ACT == 2) s = s > 0.f ? s : 0.2f * s;
  C[idx] = s;
}

// ---------- CSR build ----------
__global__ void k_count(const int* __restrict__ ei, int* __restrict__ counts) {
  int e = blockIdx.x * 256 + threadIdx.x;
  if (e >= N_E) return;
  int dst = (e < N_EDGES0) ? ei[N_EDGES0 + e] : (e - N_EDGES0);
  atomicAdd(&counts[dst], 1);
}

__global__ void k_scan(const int* __restrict__ cnt, int* __restrict__ row_ptr) {
  __shared__ int part[1024];
  int tid = threadIdx.x;
  const int CH = 30;
  int b0 = tid * CH;
  int s = 0;
  for (int i = 0; i < CH; i++) { int g = b0 + i; if (g < N_NODESX) s += cnt[g]; }
  part[tid] = s;
  __syncthreads();
  for (int off = 1; off < 1024; off <<= 1) {
    int v = (tid >= off) ? part[tid - off] : 0;
    __syncthreads();
    part[tid] += v;
    __syncthreads();
  }
  int pre = (tid > 0) ? part[tid - 1] : 0;
  for (int i = 0; i < CH; i++) {
    int g = b0 + i;
    if (g < N_NODESX) { row_ptr[g] = pre; pre += cnt[g]; }
  }
  if (tid == 1023) row_ptr[N_NODESX] = part[1023];
}

__global__ void k_fill(const int* __restrict__ ei, const int* __restrict__ row_ptr,
                       int* __restrict__ cursor, int* __restrict__ csr_src) {
  int e = blockIdx.x * 256 + threadIdx.x;
  if (e >= N_E) return;
  int src, dst;
  if (e < N_EDGES0) { src = ei[e]; dst = ei[N_EDGES0 + e]; }
  else { src = dst = e - N_EDGES0; }
  int pos = row_ptr[dst] + atomicAdd(&cursor[dst], 1);
  csr_src[pos] = src;
}

// ---------- GAT z-aggregation with FUSED edge softmax ----------
__global__ __launch_bounds__(256)
void k_gat_z(const float* __restrict__ x,
             const float* __restrict__ al_s, const float* __restrict__ al_d,
             const int* __restrict__ row_ptr, const int* __restrict__ csr_src,
             unsigned short* __restrict__ zh, unsigned short* __restrict__ zl) {
  int d = blockIdx.x, t = threadIdx.x;
  if (t >= 240) return;
  if (t >= 200) {               // zero K-pad 80..95 for each head
    int t2 = t - 200;           // 0..39
    int hd = t2 >> 2, j = t2 & 3;
    size_t o = ((size_t)hd * M_PAD + d) * KH + 80 + j * 4;
    ushort4 z4 = make_ushort4(0, 0, 0, 0);
    *(ushort4*)&zh[o] = z4;
    *(ushort4*)&zl[o] = z4;
    return;
  }
  int hd = t / 20, ch = t % 20;
  int k0 = ch * 4;
  bool full = (k0 + 2 < F_XDX);
  float ald = al_d[d * HEADSX + hd];
  float a0 = 0.f, a1 = 0.f, a2 = 0.f, a3 = 0.f, den = 0.f;
  int beg = row_ptr[d], end = row_ptr[d + 1];
  for (int j = beg; j < end; j++) {
    int s = csr_src[j];
    float v = al_s[(size_t)s * HEADSX + hd] + ald;
    v = v > 0.f ? v : 0.2f * v;
    float ex = expf(v);
    den += ex;
    const float* xr = x + (size_t)s * F_XDX + k0;
    float2 p0 = *(const float2*)xr;
    a0 += ex * p0.x; a1 += ex * p0.y;
    if (full) {
      float2 p1 = *(const float2*)(xr + 2);
      a2 += ex * p1.x; a3 += ex * p1.y;
    }
  }
  float id = 1.f / (den + 1e-16f);
  ushort4 h4, l4;
  splitbf(a0 * id, h4.x, l4.x);
  splitbf(a1 * id, h4.y, l4.y);
  splitbf(full ? a2 * id : 0.f, h4.z, l4.z);
  splitbf(full ? a3 * id : 0.f, h4.w, l4.w);
  size_t o = ((size_t)hd * M_PAD + d) * KH + k0;
  *(ushort4*)&zh[o] = h4;
  *(ushort4*)&zl[o] = l4;
}

// ---------- degree inv sqrt ----------
__global__ void k_dinv(const int* __restrict__ counts, float* __restrict__ dinv) {
  int n = blockIdx.x * 256 + threadIdx.x;
  if (n < N_NODESX) dinv[n] = rsqrtf(fmaxf((float)counts[n], 1.f));
}

// ---------- GCN aggregation (gather per dst, packed s) ----------
__global__ __launch_bounds__(256)
void k_gcn_agg(const unsigned* __restrict__ s, const float* __restrict__ dinv,
               const int* __restrict__ row_ptr, const int* __restrict__ csr_src,
               const float* __restrict__ b_gcn, float* __restrict__ out) {
  int d = blockIdx.x, t = threadIdx.x;
  if (t >= HIDX / 4) return;
  int c = t * 4;
  float4 acc = {0.f, 0.f, 0.f, 0.f};
  int beg = row_ptr[d], end = row_ptr[d + 1];
  for (int j = beg; j < end; j++) {
    int si = csr_src[j];
    float w = dinv[si];
    uint4 sv = *(const uint4*)(s + (size_t)si * HIDX + c);
    acc.x += w * unpackbf(sv.x); acc.y += w * unpackbf(sv.y);
    acc.z += w * unpackbf(sv.z); acc.w += w * unpackbf(sv.w);
  }
  float dd = dinv[d];
  float4 bb = *(const float4*)(b_gcn + c);
  float4 r;
  r.x = fmaxf(acc.x * dd + bb.x, 0.f);
  r.y = fmaxf(acc.y * dd + bb.y, 0.f);
  r.z = fmaxf(acc.z * dd + bb.z, 0.f);
  r.w = fmaxf(acc.w * dd + bb.w, 0.f);
  *(float4*)(out + (size_t)d * HIDX + c) = r;
}

// ---------- per-graph ranges: boundary detection (batch sorted, NO atomics) ----------
__global__ void k_range_init(int* __restrict__ gstart, int* __restrict__ gend) {
  int g = threadIdx.x;
  if (g < N_GRAPHSX) { gstart[g] = 0; gend[g] = 0; }
}
__global__ void k_ranges(const int* __restrict__ batch, int* __restrict__ gstart,
                         int* __restrict__ gend) {
  int n = blockIdx.x * 256 + threadIdx.x;
  if (n >= N_NODESX) return;
  int b = batch[n];
  if (n == 0) {
    gstart[b] = 0;
  } else {
    int pb = batch[n - 1];
    if (pb != b) { gend[pb] = n; gstart[b] = n; }
  }
  if (n == N_NODESX - 1) gend[b] = N_NODESX;
}

// ---------- pooling stage A ----------
__global__ __launch_bounds__(256)
void k_pool_a(const float* __restrict__ xg2, const int* __restrict__ gstart,
              const int* __restrict__ gend,
              float* __restrict__ pmax, float* __restrict__ psum) {
  int g = blockIdx.x, sl = blockIdx.y, t = threadIdx.x;
  if (t >= HIDX / 4) return;
  int c = t * 4;
  int st = gstart[g], en = gend[g];
  int len = en - st; if (len < 0) len = 0;
  int chunk = (len + NSL - 1) / NSL;
  int s0 = st + sl * chunk;
  int s1 = min(en, s0 + chunk);
  float4 mx = {0.f, 0.f, 0.f, 0.f};
  float4 sm = {0.f, 0.f, 0.f, 0.f};
  for (int n = s0; n < s1; n++) {
    float4 v = *(const float4*)(xg2 + (size_t)n * HIDX + c);
    mx.x = fmaxf(mx.x, v.x); sm.x += v.x;
    mx.y = fmaxf(mx.y, v.y); sm.y += v.y;
    mx.z = fmaxf(mx.z, v.z); sm.z += v.z;
    mx.w = fmaxf(mx.w, v.w); sm.w += v.w;
  }
  size_t o = ((size_t)g * NSL + sl) * HIDX + c;
  *(float4*)(pmax + o) = mx;
  *(float4*)(psum + o) = sm;
}

// ---------- pooling stage B ----------
__global__ __launch_bounds__(256)
void k_pool_b(const float* __restrict__ pmax, const float* __restrict__ psum,
              const int* __restrict__ gstart, const int* __restrict__ gend,
              float* __restrict__ xf) {
  int g = blockIdx.x, t = threadIdx.x;
  if (t >= HIDX / 4) return;
  int c = t * 4;
  float4 mx = {0.f, 0.f, 0.f, 0.f};
  float4 sm = {0.f, 0.f, 0.f, 0.f};
  #pragma unroll
  for (int sl = 0; sl < NSL; sl++) {
    size_t o = ((size_t)g * NSL + sl) * HIDX + c;
    float4 m = *(const float4*)(pmax + o);
    float4 s = *(const float4*)(psum + o);
    mx.x = fmaxf(mx.x, m.x); sm.x += s.x;
    mx.y = fmaxf(mx.y, m.y); sm.y += s.y;
    mx.z = fmaxf(mx.z, m.z); sm.z += s.z;
    mx.w = fmaxf(mx.w, m.w); sm.w += s.w;
  }
  int st = gstart[g], en = gend[g];
  float inv = (en > st) ? 1.f / (float)(en - st) : 0.f;
  float* xr = xf + (size_t)g * (2 * HIDX);
  float4 mean; mean.x = sm.x*inv; mean.y = sm.y*inv; mean.z = sm.z*inv; mean.w = sm.w*inv;
  *(float4*)(xr + c) = mx;
  *(float4*)(xr + HIDX + c) = mean;
}

// ---------- label branch ----------
__global__ void k_dvec(const float* __restrict__ A, float* __restrict__ dvec) {
  int i = blockIdx.x * 64 + threadIdx.x;
  if (i >= N_CLASSESX) return;
  float s = 0.f;
  for (int j = 0; j < N_CLASSESX; j++) s += A[i * N_CLASSESX + j];
  dvec[i] = rsqrtf(s);
}
__global__ void k_adj(const float* __restrict__ A, const float* __restrict__ dvec,
                      float* __restrict__ adj) {
  int idx = blockIdx.x * 256 + threadIdx.x;
  if (idx >= N_CLASSESX * N_CLASSESX) return;
  int i = idx / N_CLASSESX, j = idx % N_CLASSESX;
  adj[idx] = dvec[i] * A[j * N_CLASSESX + i] * dvec[j];
}

// ---------- final out = fc2o @ y^T : one wave per output ----------
__global__ __launch_bounds__(256)
void k_out(const float* __restrict__ xf2, const float* __restrict__ y,
           float* __restrict__ out) {
  int gw = (blockIdx.x * 256 + threadIdx.x) >> 6;
  int lane = threadIdx.x & 63;
  if (gw >= N_GRAPHSX * N_CLASSESX) return;
  int b = gw / N_CLASSESX, c = gw - b * N_CLASSESX;
  const float4* xr = (const float4*)(xf2 + (size_t)b * 1024);
  const float4* yr = (const float4*)(y + (size_t)c * 1024);
  float s = 0.f;
  #pragma unroll
  for (int i = 0; i < 4; i++) {
    float4 xv = xr[lane + i * 64], yv = yr[lane + i * 64];
    s += xv.x*yv.x + xv.y*yv.y + xv.z*yv.z + xv.w*yv.w;
  }
  #pragma unroll
  for (int off = 32; off > 0; off >>= 1) s += __shfl_down(s, off, 64);
  if (lane == 0) out[gw] = s;
}

// =======================================================================
extern "C" void kernel_launch(void* const* d_in, const int* in_sizes, int n_in,
                              void* d_out, int out_size, void* d_ws, size_t ws_size,
                              hipStream_t stream) {
  const float* x     = (const float*)d_in[0];
  const int*   ei    = (const int*)d_in[1];
  const int*   batch = (const int*)d_in[2];
  const float* inp   = (const float*)d_in[3];
  const float* W_gat = (const float*)d_in[4];
  const float* a_src = (const float*)d_in[5];
  const float* a_dst = (const float*)d_in[6];
  const float* b_gat = (const float*)d_in[7];
  const float* W_gcn = (const float*)d_in[8];
  const float* b_gcn = (const float*)d_in[9];
  const float* W_fc1 = (const float*)d_in[10];
  const float* b_fc1 = (const float*)d_in[11];
  const float* W_fc2 = (const float*)d_in[12];
  const float* b_fc2 = (const float*)d_in[13];
  const float* W_gc1 = (const float*)d_in[14];
  const float* W_gc2 = (const float*)d_in[15];
  const float* A     = (const float*)d_in[16];
  float* out = (float*)d_out;

  char* ws = (char*)d_ws;
  size_t off = 0;
  auto alloc = [&](size_t bytes) -> void* {
    void* p = ws + off;
    off = (off + bytes + 255) & ~(size_t)255;
    return p;
  };

  // regionA: zh|zl planes [10][M_PAD][KH] (GAT phase), then s packed (GCN phase)
  char* regionA = (char*)alloc((size_t)10 * M_PAD * KH * 2 * 2);
  unsigned short* zh = (unsigned short*)regionA;
  unsigned short* zl = zh + (size_t)10 * M_PAD * KH;
  unsigned* spk = (unsigned*)regionA;                        // 93.6MB <= 115.5MB
  // regionB: xgh|xgl [M_PAD][800] planes, then xg2 fp32 [30000][780]
  char* regionB = (char*)alloc((size_t)M_PAD * KP_GCN * 2 * 2);
  unsigned short* xgh = (unsigned short*)regionB;
  unsigned short* xgl = xgh + (size_t)M_PAD * KP_GCN;
  float* xg2 = (float*)regionB;                              // 93.6MB <= 96.3MB

  float* al_s   = (float*)alloc(sizeof(float) * N_NODESX * HEADSX);
  float* al_d   = (float*)alloc(sizeof(float) * N_NODESX * HEADSX);
  int* counts   = (int*)alloc(sizeof(int) * N_NODESX);
  int* row_ptr  = (int*)alloc(sizeof(int) * (N_NODESX + 1));
  int* cursor   = (int*)alloc(sizeof(int) * N_NODESX);
  int* csr_src  = (int*)alloc(sizeof(int) * N_E);
  float* dinv   = (float*)alloc(sizeof(float) * N_NODESX);
  int* gstart   = (int*)alloc(sizeof(int) * N_GRAPHSX);
  int* gend     = (int*)alloc(sizeof(int) * N_GRAPHSX);
  float* xf     = (float*)alloc(sizeof(float) * N_GRAPHSX * 2 * HIDX);
  float* fc1o   = (float*)alloc(sizeof(float) * N_GRAPHSX * 1500);
  float* fc2o   = (float*)alloc(sizeof(float) * N_GRAPHSX * 1024);
  float* t1     = (float*)alloc(sizeof(float) * N_CLASSESX * 1024);
  float* adj    = (float*)alloc(sizeof(float) * N_CLASSESX * N_CLASSESX);
  float* dvec   = (float*)alloc(sizeof(float) * N_CLASSESX);
  float* y1     = (float*)alloc(sizeof(float) * N_CLASSESX * 1024);
  float* t2     = (float*)alloc(sizeof(float) * N_CLASSESX * 1024);
  float* ybuf   = (float*)alloc(sizeof(float) * N_CLASSESX * 1024);
  float* Ppart  = (float*)alloc(sizeof(float) * 13 * 64 * 1500);
  unsigned short* wcTh = (unsigned short*)alloc(sizeof(short) * (size_t)N_PAD * KP_GCN);
  unsigned short* wcTl = (unsigned short*)alloc(sizeof(short) * (size_t)N_PAD * KP_GCN);
  unsigned short* whTh = (unsigned short*)alloc(sizeof(short) * HEADSX * 128 * KH);
  unsigned short* whTl = (unsigned short*)alloc(sizeof(short) * HEADSX * 128 * KH);
  float* w_as = (float*)alloc(sizeof(float) * HEADSX * F_XDX);
  float* w_ad = (float*)alloc(sizeof(float) * HEADSX * F_XDX);
  // pooling partials alias Ppart (disjoint lifetimes, 3.19MB <= 4.99MB)
  float* pmax = Ppart;
  float* psum = Ppart + (size_t)N_GRAPHSX * NSL * HIDX;
  (void)ws_size; (void)in_sizes; (void)n_in; (void)out_size;

  hipMemsetAsync(counts, 0, sizeof(int) * N_NODESX, stream);
  hipMemsetAsync(cursor, 0, sizeof(int) * N_NODESX, stream);

  // weight prep
  k_splitT<<<(N_PAD * (KP_GCN/8) + 255) / 256, 256, 0, stream>>>(
      W_gcn, HIDX, HIDX, N_PAD, KP_GCN, wcTh, wcTl);
  k_splitT_heads<<<(HEADSX * 128 * (KH/8) + 255) / 256, 256, 0, stream>>>(W_gat, whTh, whTl);
  k_wal<<<(HEADSX * F_XDX + 255) / 256, 256, 0, stream>>>(W_gat, a_src, a_dst, w_as, w_ad);

  // attention logits directly from x (h never materialized)
  k_al2<<<(N_NODESX * HEADSX + 255) / 256, 256, 0, stream>>>(x, w_as, w_ad, al_s, al_d);
  // CSR
  k_count<<<(N_E + 255) / 256, 256, 0, stream>>>(ei, counts);
  k_scan<<<1, 1024, 0, stream>>>(counts, row_ptr);
  k_fill<<<(N_E + 255) / 256, 256, 0, stream>>>(ei, row_ptr, cursor, csr_src);
  // GAT: fused edge-softmax + x-aggregation into z planes, then per-head GEMM
  k_gat_z<<<N_NODESX, 256, 0, stream>>>(x, al_s, al_d, row_ptr, csr_src, zh, zl);
  gemm_head<<<dim3(1, M_PAD / 128, HEADSX), 256, 0, stream>>>(
      zh, zl, whTh, whTl, b_gat, xgh, xgl);
  k_zero_xgpad<<<(M_PAD * 5 + 255) / 256, 256, 0, stream>>>(xgh, xgl);
  // GCN
  k_dinv<<<(N_NODESX + 255) / 256, 256, 0, stream>>>(counts, dinv);
  gemm_mfma3<<<dim3(N_PAD / 128, M_PAD / 128), 256, 0, stream>>>(
      xgh, xgl, wcTh, wcTl, spk, N_NODESX, HIDX, KP_GCN);
  k_gcn_agg<<<N_NODESX, 256, 0, stream>>>(spk, dinv, row_ptr, csr_src, b_gcn, xg2);
  // pooling (2-stage; ranges via boundary detection, no atomics)
  k_range_init<<<1, 64, 0, stream>>>(gstart, gend);
  k_ranges<<<(N_NODESX + 255) / 256, 256, 0, stream>>>(batch, gstart, gend);
  k_pool_a<<<dim3(N_GRAPHSX, NSL), 256, 0, stream>>>(xg2, gstart, gend, pmax, psum);
  k_pool_b<<<N_GRAPHSX, 256, 0, stream>>>(pmax, psum, gstart, gend, xf);

  // ---- dense head via split-K ----
  gemm_sk<<<dim3(24, 1, 13), 256, 0, stream>>>(xf, W_fc1, Ppart, 64, 1500, 1560, 128);
  k_sk_reduce<1, true><<<(64 * 1500 + 255) / 256, 256, 0, stream>>>(
      Ppart, b_fc1, fc1o, 64 * 1500, 1500, 13);
  gemm_sk<<<dim3(16, 1, 12), 256, 0, stream>>>(fc1o, W_fc2, Ppart, 64, 1024, 1500, 128);
  k_sk_reduce<0, true><<<(64 * 1024 + 255) / 256, 256, 0, stream>>>(
      Ppart, b_fc2, fc2o, 64 * 1024, 1024, 12);

  // ---- label branch ----
  k_dvec<<<(N_CLASSESX + 63) / 64, 64, 0, stream>>>(A, dvec);
  k_adj<<<(N_CLASSESX * N_CLASSESX + 255) / 256, 256, 0, stream>>>(A, dvec, adj);
  gemm_sk<<<dim3(16, 2, 5), 256, 0, stream>>>(inp, W_gc1, Ppart, 100, 1024, 300, 64);
  k_sk_reduce<0, false><<<(100 * 1024 + 255) / 256, 256, 0, stream>>>(
      Ppart, nullptr, t1, 100 * 1024, 1024, 5);
  gemm_sk<<<dim3(16, 2, 4), 256, 0, stream>>>(adj, t1, Ppart, 100, 1024, 100, 32);
  k_sk_reduce<2, false><<<(100 * 1024 + 255) / 256, 256, 0, stream>>>(
      Ppart, nullptr, y1, 100 * 1024, 1024, 4);
  gemm_sk<<<dim3(16, 2, 8), 256, 0, stream>>>(y1, W_gc2, Ppart, 100, 1024, 1024, 128);
  k_sk_reduce<0, false><<<(100 * 1024 + 255) / 256, 256, 0, stream>>>(
      Ppart, nullptr, t2, 100 * 1024, 1024, 8);
  gemm_sk<<<dim3(16, 2, 4), 256, 0, stream>>>(adj, t2, Ppart, 100, 1024, 100, 32);
  k_sk_reduce<0, false><<<(100 * 1024 + 255) / 256, 256, 0, stream>>>(
      Ppart, nullptr, ybuf, 100 * 1024, 1024, 4);

  // out = fc2o @ ybuf^T (wave per output)
  k_out<<<(N_GRAPHSX * N_CLASSESX * 64 + 255) / 256, 256, 0, stream>>>(fc2o, ybuf, out);
}

// Round 14
// 783.207 us; speedup vs baseline: 1.0461x; 1.0070x over previous
//
#include <hip/hip_runtime.h>

#define N_NODESX 30000
#define M_PAD    30080   // ceil(30000/128)*128
#define N_EDGES0 300000
#define N_E      330000
#define N_GRAPHSX 64
#define N_CLASSESX 100
#define F_XDX 78
#define HEADSX 10
#define HIDX 780
#define N_PAD 896        // ceil(780/128)*128
#define IN_CHX 300
#define KP_GCN 800   // ceil(780/32)*32
#define KH 96        // per-head K pad: ceil(78/32)*32
#define NXCD 8
#define NSL 8        // pooling node-slices per graph

typedef __attribute__((ext_vector_type(8))) short short8v;
typedef __attribute__((ext_vector_type(8))) unsigned short ushort8v;
typedef __attribute__((ext_vector_type(4))) float f32x4;

// ---------- bf16 split helpers ----------
__device__ inline unsigned short f2bf_rne(float f) {
  unsigned u = __float_as_uint(f);
  unsigned r = (u + 0x7FFFu + ((u >> 16) & 1u)) >> 16;
  return (unsigned short)r;
}
__device__ inline float bf2f(unsigned short h) {
  return __uint_as_float(((unsigned)h) << 16);
}
__device__ inline void splitbf(float v, unsigned short& h, unsigned short& l) {
  unsigned short hh = f2bf_rne(v);
  h = hh;
  l = f2bf_rne(v - bf2f(hh));
}
__device__ inline unsigned packbf(float v) {
  unsigned short hh, ll;
  splitbf(v, hh, ll);
  return ((unsigned)hh << 16) | (unsigned)ll;
}
__device__ inline float unpackbf(unsigned u) {
  return __uint_as_float(u & 0xFFFF0000u) + __uint_as_float(u << 16);
}

// ---------- split + transpose: W (K x N) -> planes (Npad x Kp, zero pad) ----------
__global__ void k_splitT(const float* __restrict__ W, int K, int N, int Npad, int Kp,
                         unsigned short* __restrict__ Th, unsigned short* __restrict__ Tl) {
  int idx = blockIdx.x * 256 + threadIdx.x;
  int packs = Kp >> 3;
  if (idx >= Npad * packs) return;
  int n = idx / packs, p = idx - n * packs;
  ushort8v h, l;
  #pragma unroll
  for (int j = 0; j < 8; j++) {
    int k = p * 8 + j;
    float v = (n < N && k < K) ? W[(size_t)k * N + n] : 0.f;
    unsigned short hh, ll;
    splitbf(v, hh, ll);
    h[j] = hh; l[j] = ll;
  }
  *(ushort8v*)&Th[(size_t)n * Kp + p * 8] = h;
  *(ushort8v*)&Tl[(size_t)n * Kp + p * 8] = l;
}

// ---------- per-head W_gat planes: [10][128][KH] hi/lo ----------
__global__ void k_splitT_heads(const float* __restrict__ W,
                               unsigned short* __restrict__ Th, unsigned short* __restrict__ Tl) {
  int idx = blockIdx.x * 256 + threadIdx.x;
  const int packs = KH >> 3;                           // 12
  if (idx >= HEADSX * 128 * packs) return;
  int hd = idx / (128 * packs);
  int rem = idx - hd * 128 * packs;
  int n = rem / packs, p = rem - n * packs;
  ushort8v h, l;
  #pragma unroll
  for (int j = 0; j < 8; j++) {
    int k = p * 8 + j;
    float v = (n < F_XDX && k < F_XDX) ? W[(size_t)k * HIDX + hd * F_XDX + n] : 0.f;
    unsigned short hh, ll;
    splitbf(v, hh, ll);
    h[j] = hh; l[j] = ll;
  }
  size_t o = ((size_t)hd * 128 + n) * KH + p * 8;
  *(ushort8v*)&Th[o] = h;
  *(ushort8v*)&Tl[o] = l;
}

// ---------- attention weight fold ----------
__global__ void k_wal(const float* __restrict__ W, const float* __restrict__ a_src,
                      const float* __restrict__ a_dst,
                      float* __restrict__ w_as, float* __restrict__ w_ad) {
  int idx = blockIdx.x * 256 + threadIdx.x;
  if (idx >= HEADSX * F_XDX) return;
  int hd = idx / F_XDX, k = idx - hd * F_XDX;
  const float* wr = W + (size_t)k * HIDX + hd * F_XDX;
  const float* as = a_src + hd * F_XDX;
  const float* ad = a_dst + hd * F_XDX;
  float s1 = 0.f, s2 = 0.f;
  for (int c = 0; c < F_XDX; c++) { float w = wr[c]; s1 += w * as[c]; s2 += w * ad[c]; }
  w_as[idx] = s1; w_ad[idx] = s2;
}

// ---------- attention logits ----------
__global__ void k_al2(const float* __restrict__ x, const float* __restrict__ w_as,
                      const float* __restrict__ w_ad,
                      float* __restrict__ al_s, float* __restrict__ al_d) {
  int idx = blockIdx.x * 256 + threadIdx.x;
  if (idx >= N_NODESX * HEADSX) return;
  int n = idx / HEADSX, hd = idx - n * HEADSX;
  const float2* xr = (const float2*)(x + (size_t)n * F_XDX);
  const float2* ws = (const float2*)(w_as + hd * F_XDX);
  const float2* wd = (const float2*)(w_ad + hd * F_XDX);
  float s1 = 0.f, s2 = 0.f;
  #pragma unroll 13
  for (int i = 0; i < F_XDX / 2; i++) {
    float2 v = xr[i], a = ws[i], d = wd[i];
    s1 += v.x * a.x + v.y * a.y;
    s2 += v.x * d.x + v.y * d.y;
  }
  al_s[idx] = s1; al_d[idx] = s2;
}

// ---------- MFMA split-bf16 GEMM (GCN), tile 128x128x32, 2-phase dbuf + g_l_lds + XCD swizzle ----------
// [R11/R13 proven config: ~161 us, 789 TF effective — ceiling of 2-phase template]
__global__ __launch_bounds__(256)
void gemm_mfma3(const unsigned short* __restrict__ Ah, const unsigned short* __restrict__ Al,
                const unsigned short* __restrict__ Bh, const unsigned short* __restrict__ Bl,
                unsigned* __restrict__ C, int M, int N, int Kp) {
  __shared__ unsigned short lds[2 * 16384];
  const int tid  = threadIdx.x;
  const int lane = tid & 63;
  const int w    = tid >> 6;
  const int wr   = w >> 1, wc = w & 1;

  const int nwg = gridDim.x * gridDim.y;
  const int L   = blockIdx.y * gridDim.x + blockIdx.x;
  const int qq = nwg / NXCD, rr8 = nwg % NXCD;
  const int xcd = L % NXCD, pos = L / NXCD;
  const int newL = (xcd < rr8 ? xcd * (qq + 1) : rr8 * (qq + 1) + (xcd - rr8) * qq) + pos;
  const int bm = (newL / gridDim.x) * 128;
  const int bn = (newL % gridDim.x) * 128;

  f32x4 acc[4][4];
  #pragma unroll
  for (int m = 0; m < 4; m++)
    #pragma unroll
    for (int n = 0; n < 4; n++) acc[m][n] = (f32x4){0.f, 0.f, 0.f, 0.f};

  const unsigned short* srcs[4] = {Ah, Al, Bh, Bl};

#define STAGE(buf, k0)                                                         \
  {                                                                            \
    _Pragma("unroll")                                                          \
    for (int i = 0; i < 8; i++) {                                              \
      const int plane = i >> 1;                                                \
      const int qp = ((i & 1) << 8) + tid;                                     \
      const int fm = qp >> 6;                                                  \
      const int ks = (qp & 63) >> 4, r16 = qp & 15;                            \
      const int rowbase = (plane < 2) ? bm : bn;                               \
      const int row = rowbase + fm * 16 + r16;                                 \
      const unsigned short* gp = srcs[plane] + (size_t)row * Kp + (k0) + ks * 8; \
      unsigned short* lp = (unsigned short*)lds + (buf) * 16384 + plane * 4096 \
                           + (((i & 1) << 8) + (w << 6)) * 8;                  \
      __builtin_amdgcn_global_load_lds(                                        \
          (const __attribute__((address_space(1))) unsigned int*)gp,           \
          (__attribute__((address_space(3))) unsigned int*)lp, 16, 0, 0);      \
    }                                                                          \
  }

  const int nt = Kp >> 5;
  STAGE(0, 0);
  __syncthreads();
  int cur = 0;
  for (int t = 0; t < nt; ++t) {
    if (t + 1 < nt) STAGE(cur ^ 1, (t + 1) << 5);
    const unsigned short* Lb = (const unsigned short*)lds + cur * 16384;
    short8v afh[4], afl[4], bfh[4], bfl[4];
    #pragma unroll
    for (int m = 0; m < 4; m++) {
      int fmA = wr * 4 + m;
      afh[m] = *(const short8v*)&Lb[0 * 4096 + fmA * 512 + lane * 8];
      afl[m] = *(const short8v*)&Lb[1 * 4096 + fmA * 512 + lane * 8];
    }
    #pragma unroll
    for (int n = 0; n < 4; n++) {
      int fnB = wc * 4 + n;
      bfh[n] = *(const short8v*)&Lb[2 * 4096 + fnB * 512 + lane * 8];
      bfl[n] = *(const short8v*)&Lb[3 * 4096 + fnB * 512 + lane * 8];
    }
    #pragma unroll
    for (int m = 0; m < 4; m++) {
      #pragma unroll
      for (int n = 0; n < 4; n++) {
        acc[m][n] = __builtin_amdgcn_mfma_f32_16x16x32_bf16(afh[m], bfh[n], acc[m][n], 0, 0, 0);
        acc[m][n] = __builtin_amdgcn_mfma_f32_16x16x32_bf16(afh[m], bfl[n], acc[m][n], 0, 0, 0);
        acc[m][n] = __builtin_amdgcn_mfma_f32_16x16x32_bf16(afl[m], bfh[n], acc[m][n], 0, 0, 0);
      }
    }
    __syncthreads();
    cur ^= 1;
  }
#undef STAGE

  // epilogue: C/D layout col = lane&15, row = (lane>>4)*4 + r  [m89-verified]
  const int r0 = (lane >> 4) * 4;
  const int cc = lane & 15;
  #pragma unroll
  for (int m = 0; m < 4; m++) {
    #pragma unroll
    for (int n = 0; n < 4; n++) {
      int gcol = bn + (wc * 4 + n) * 16 + cc;
      if (gcol >= N) continue;
      #pragma unroll
      for (int r2 = 0; r2 < 4; r2++) {
        int grow = bm + (wr * 4 + m) * 16 + r0 + r2;
        if (grow < M) C[(size_t)grow * N + gcol] = packbf(acc[m][n][r2]);
      }
    }
  }
}

// ---------- per-head MFMA GEMM: xg_hd = relu(z_hd @ W_hd + b) -> split planes ----------
__global__ __launch_bounds__(256)
void gemm_head(const unsigned short* __restrict__ Zh, const unsigned short* __restrict__ Zl,
               const unsigned short* __restrict__ Wh, const unsigned short* __restrict__ Wl,
               const float* __restrict__ bias,
               unsigned short* __restrict__ Ch, unsigned short* __restrict__ Cl) {
  __shared__ unsigned short lds[2 * 16384];
  const int tid  = threadIdx.x;
  const int lane = tid & 63;
  const int w    = tid >> 6;
  const int wr   = w >> 1, wc = w & 1;
  const int hd = blockIdx.z;
  const int bm = blockIdx.y * 128;

  const unsigned short* srcs[4] = {
    Zh + (size_t)hd * M_PAD * KH, Zl + (size_t)hd * M_PAD * KH,
    Wh + (size_t)hd * 128 * KH,   Wl + (size_t)hd * 128 * KH };

  f32x4 acc[4][4];
  #pragma unroll
  for (int m = 0; m < 4; m++)
    #pragma unroll
    for (int n = 0; n < 4; n++) acc[m][n] = (f32x4){0.f, 0.f, 0.f, 0.f};

#define STAGEH(buf, k0)                                                        \
  {                                                                            \
    _Pragma("unroll")                                                          \
    for (int i = 0; i < 8; i++) {                                              \
      const int plane = i >> 1;                                                \
      const int qp = ((i & 1) << 8) + tid;                                     \
      const int fm = qp >> 6;                                                  \
      const int ks = (qp & 63) >> 4, r16 = qp & 15;                            \
      const int row = ((plane < 2) ? bm : 0) + fm * 16 + r16;                  \
      const unsigned short* gp = srcs[plane] + (size_t)row * KH + (k0) + ks * 8; \
      unsigned short* lp = (unsigned short*)lds + (buf) * 16384 + plane * 4096 \
                           + (((i & 1) << 8) + (w << 6)) * 8;                  \
      __builtin_amdgcn_global_load_lds(                                        \
          (const __attribute__((address_space(1))) unsigned int*)gp,           \
          (__attribute__((address_space(3))) unsigned int*)lp, 16, 0, 0);      \
    }                                                                          \
  }

  const int nt = KH >> 5;   // 3
  STAGEH(0, 0);
  __syncthreads();
  int cur = 0;
  for (int t = 0; t < nt; ++t) {
    if (t + 1 < nt) STAGEH(cur ^ 1, (t + 1) << 5);
    const unsigned short* Lb = (const unsigned short*)lds + cur * 16384;
    short8v afh[4], afl[4], bfh[4], bfl[4];
    #pragma unroll
    for (int m = 0; m < 4; m++) {
      int fmA = wr * 4 + m;
      afh[m] = *(const short8v*)&Lb[0 * 4096 + fmA * 512 + lane * 8];
      afl[m] = *(const short8v*)&Lb[1 * 4096 + fmA * 512 + lane * 8];
    }
    #pragma unroll
    for (int n = 0; n < 4; n++) {
      int fnB = wc * 4 + n;
      bfh[n] = *(const short8v*)&Lb[2 * 4096 + fnB * 512 + lane * 8];
      bfl[n] = *(const short8v*)&Lb[3 * 4096 + fnB * 512 + lane * 8];
    }
    #pragma unroll
    for (int m = 0; m < 4; m++) {
      #pragma unroll
      for (int n = 0; n < 4; n++) {
        acc[m][n] = __builtin_amdgcn_mfma_f32_16x16x32_bf16(afh[m], bfh[n], acc[m][n], 0, 0, 0);
        acc[m][n] = __builtin_amdgcn_mfma_f32_16x16x32_bf16(afh[m], bfl[n], acc[m][n], 0, 0, 0);
        acc[m][n] = __builtin_amdgcn_mfma_f32_16x16x32_bf16(afl[m], bfh[n], acc[m][n], 0, 0, 0);
      }
    }
    __syncthreads();
    cur ^= 1;
  }
#undef STAGEH

  const int r0 = (lane >> 4) * 4;
  const int cc = lane & 15;
  #pragma unroll
  for (int n = 0; n < 4; n++) {
    int gcol = (wc * 4 + n) * 16 + cc;     // 0..127
    if (gcol >= F_XDX) continue;
    float bb = bias[hd * F_XDX + gcol];
    #pragma unroll
    for (int m = 0; m < 4; m++) {
      #pragma unroll
      for (int r2 = 0; r2 < 4; r2++) {
        int grow = bm + (wr * 4 + m) * 16 + r0 + r2;
        if (grow >= N_NODESX) continue;
        float v = fmaxf(acc[m][n][r2] + bb, 0.f);
        unsigned short hh, ll;
        splitbf(v, hh, ll);
        size_t o = (size_t)grow * KP_GCN + hd * F_XDX + gcol;
        Ch[o] = hh; Cl[o] = ll;
      }
    }
  }
}

// ---------- zero xgh/xgl K-pad cols 780..799 ----------
__global__ void k_zero_xgpad(unsigned short* __restrict__ Ch, unsigned short* __restrict__ Cl) {
  int idx = blockIdx.x * 256 + threadIdx.x;
  if (idx >= M_PAD * 5) return;
  int row = idx / 5, j = idx - row * 5;
  size_t o = (size_t)row * KP_GCN + 780 + j * 4;
  ushort4 z = make_ushort4(0, 0, 0, 0);
  *(ushort4*)&Ch[o] = z;
  *(ushort4*)&Cl[o] = z;
}

// ---------- split-K fp32 GEMM for skinny-M ----------
__global__ __launch_bounds__(256)
void gemm_sk(const float* __restrict__ A, const float* __restrict__ B,
             float* __restrict__ P, int M, int N, int K, int SK) {
  __shared__ float As[16][64];
  __shared__ float Bs[16][64];
  int tid = threadIdx.x;
  int bm = blockIdx.y * 64;
  int bn = blockIdx.x * 64;
  int ks = blockIdx.z * SK;
  int ke = min(K, ks + SK);
  int tr = tid >> 4;
  int tc = tid & 15;
  float acc[4][4] = {{0.f}};
  int la_m = tid >> 2;
  int la_k = (tid & 3) << 2;
  int lb_k4 = (tid >> 6) << 2;
  int lb_n = tid & 63;

  for (int k0 = ks; k0 < ke; k0 += 16) {
    {
      int gm = bm + la_m;
      bool mok = gm < M;
      const float* ap = A + (size_t)gm * K + k0 + la_k;
      #pragma unroll
      for (int q = 0; q < 4; q++) {
        int kk = la_k + q;
        As[kk][la_m] = (mok && (k0 + kk) < ke) ? ap[q] : 0.f;
      }
    }
    {
      int gn = bn + lb_n;
      #pragma unroll
      for (int q = 0; q < 4; q++) {
        int kk = lb_k4 + q;
        int gk = k0 + kk;
        Bs[kk][lb_n] = (gk < ke && gn < N) ? B[(size_t)gk * N + gn] : 0.f;
      }
    }
    __syncthreads();
    #pragma unroll
    for (int kk = 0; kk < 16; kk++) {
      float a0 = As[kk][tr*4+0], a1 = As[kk][tr*4+1],
            a2 = As[kk][tr*4+2], a3 = As[kk][tr*4+3];
      float b0 = Bs[kk][tc*4+0], b1 = Bs[kk][tc*4+1],
            b2 = Bs[kk][tc*4+2], b3 = Bs[kk][tc*4+3];
      acc[0][0] += a0*b0; acc[0][1] += a0*b1; acc[0][2] += a0*b2; acc[0][3] += a0*b3;
      acc[1][0] += a1*b0; acc[1][1] += a1*b1; acc[1][2] += a1*b2; acc[1][3] += a1*b3;
      acc[2][0] += a2*b0; acc[2][1] += a2*b1; acc[2][2] += a2*b2; acc[2][3] += a2*b3;
      acc[3][0] += a3*b0; acc[3][1] += a3*b1; acc[3][2] += a3*b2; acc[3][3] += a3*b3;
    }
    __syncthreads();
  }
  float* Pp = P + (size_t)blockIdx.z * M * N;
  #pragma unroll
  for (int i = 0; i < 4; i++) {
    int gm = bm + tr*4 + i;
    if (gm >= M) continue;
    #pragma unroll
    for (int j = 0; j < 4; j++) {
      int gn = bn + tc*4 + j;
      if (gn >= N) continue;
      Pp[(size_t)gm * N + gn] = acc[i][j];
    }
  }
}

template<int ACT, bool HAS_BIAS>
__global__ void k_sk_reduce(const float* __restrict__ P, const float* __restrict__ bias,
                            float* __restrict__ C, int MN, int N, int nS) {
  int idx = blockIdx.x * 256 + threadIdx.x;
  if (idx >= MN) return;
  float s = 0.f;
  for (int sl = 0; sl < nS; sl++) s += P[(size_t)sl * MN + idx];
  if (HAS_BIAS) s += bias[idx % N];
  if (ACT == 1) s = fmaxf(s, 0.f);
  else if (ACT == 2) s = s > 0.f ? s : 0.2f * s;
  C[idx] = s;
}

// ---------- CSR build ----------
__global__ void k_count(const int* __restrict__ ei, int* __restrict__ counts) {
  int e = blockIdx.x * 256 + threadIdx.x;
  if (e >= N_E) return;
  int dst = (e < N_EDGES0) ? ei[N_EDGES0 + e] : (e - N_EDGES0);
  atomicAdd(&counts[dst], 1);
}

__global__ void k_scan(const int* __restrict__ cnt, int* __restrict__ row_ptr) {
  __shared__ int part[1024];
  int tid = threadIdx.x;
  const int CH = 30;
  int b0 = tid * CH;
  int s = 0;
  for (int i = 0; i < CH; i++) { int g = b0 + i; if (g < N_NODESX) s += cnt[g]; }
  part[tid] = s;
  __syncthreads();
  for (int off = 1; off < 1024; off <<= 1) {
    int v = (tid >= off) ? part[tid - off] : 0;
    __syncthreads();
    part[tid] += v;
    __syncthreads();
  }
  int pre = (tid > 0) ? part[tid - 1] : 0;
  for (int i = 0; i < CH; i++) {
    int g = b0 + i;
    if (g < N_NODESX) { row_ptr[g] = pre; pre += cnt[g]; }
  }
  if (tid == 1023) row_ptr[N_NODESX] = part[1023];
}

__global__ void k_fill(const int* __restrict__ ei, const int* __restrict__ row_ptr,
                       int* __restrict__ cursor, int* __restrict__ csr_src) {
  int e = blockIdx.x * 256 + threadIdx.x;
  if (e >= N_E) return;
  int src, dst;
  if (e < N_EDGES0) { src = ei[e]; dst = ei[N_EDGES0 + e]; }
  else { src = dst = e - N_EDGES0; }
  int pos = row_ptr[dst] + atomicAdd(&cursor[dst], 1);
  csr_src[pos] = src;
}

// ---------- GAT z-aggregation with FUSED edge softmax (2-way unrolled gather) ----------
__global__ __launch_bounds__(256)
void k_gat_z(const float* __restrict__ x,
             const float* __restrict__ al_s, const float* __restrict__ al_d,
             const int* __restrict__ row_ptr, const int* __restrict__ csr_src,
             unsigned short* __restrict__ zh, unsigned short* __restrict__ zl) {
  int d = blockIdx.x, t = threadIdx.x;
  if (t >= 240) return;
  if (t >= 200) {               // zero K-pad 80..95 for each head
    int t2 = t - 200;           // 0..39
    int hd = t2 >> 2, j = t2 & 3;
    size_t o = ((size_t)hd * M_PAD + d) * KH + 80 + j * 4;
    ushort4 z4 = make_ushort4(0, 0, 0, 0);
    *(ushort4*)&zh[o] = z4;
    *(ushort4*)&zl[o] = z4;
    return;
  }
  int hd = t / 20, ch = t % 20;
  int k0 = ch * 4;
  bool full = (k0 + 2 < F_XDX);
  float ald = al_d[d * HEADSX + hd];
  float a0 = 0.f, a1 = 0.f, a2 = 0.f, a3 = 0.f, den = 0.f;
  int beg = row_ptr[d], end = row_ptr[d + 1];
  int j = beg;
  for (; j + 1 < end; j += 2) {
    int s0 = csr_src[j], s1 = csr_src[j + 1];
    float v0 = al_s[(size_t)s0 * HEADSX + hd] + ald;
    float v1 = al_s[(size_t)s1 * HEADSX + hd] + ald;
    v0 = v0 > 0.f ? v0 : 0.2f * v0;
    v1 = v1 > 0.f ? v1 : 0.2f * v1;
    float ex0 = expf(v0), ex1 = expf(v1);
    den += ex0 + ex1;
    const float* xr0 = x + (size_t)s0 * F_XDX + k0;
    const float* xr1 = x + (size_t)s1 * F_XDX + k0;
    float2 p00 = *(const float2*)xr0;
    float2 p10 = *(const float2*)xr1;
    a0 += ex0 * p00.x + ex1 * p10.x;
    a1 += ex0 * p00.y + ex1 * p10.y;
    if (full) {
      float2 p01 = *(const float2*)(xr0 + 2);
      float2 p11 = *(const float2*)(xr1 + 2);
      a2 += ex0 * p01.x + ex1 * p11.x;
      a3 += ex0 * p01.y + ex1 * p11.y;
    }
  }
  if (j < end) {
    int s = csr_src[j];
    float v = al_s[(size_t)s * HEADSX + hd] + ald;
    v = v > 0.f ? v : 0.2f * v;
    float ex = expf(v);
    den += ex;
    const float* xr = x + (size_t)s * F_XDX + k0;
    float2 p0 = *(const float2*)xr;
    a0 += ex * p0.x; a1 += ex * p0.y;
    if (full) {
      float2 p1 = *(const float2*)(xr + 2);
      a2 += ex * p1.x; a3 += ex * p1.y;
    }
  }
  float id = 1.f / (den + 1e-16f);
  ushort4 h4, l4;
  splitbf(a0 * id, h4.x, l4.x);
  splitbf(a1 * id, h4.y, l4.y);
  splitbf(full ? a2 * id : 0.f, h4.z, l4.z);
  splitbf(full ? a3 * id : 0.f, h4.w, l4.w);
  size_t o = ((size_t)hd * M_PAD + d) * KH + k0;
  *(ushort4*)&zh[o] = h4;
  *(ushort4*)&zl[o] = l4;
}

// ---------- degree inv sqrt ----------
__global__ void k_dinv(const int* __restrict__ counts, float* __restrict__ dinv) {
  int n = blockIdx.x * 256 + threadIdx.x;
  if (n < N_NODESX) dinv[n] = rsqrtf(fmaxf((float)counts[n], 1.f));
}

// ---------- GCN aggregation (gather per dst, packed s; 4-way unrolled for MLP) ----------
__global__ __launch_bounds__(256)
void k_gcn_agg(const unsigned* __restrict__ s, const float* __restrict__ dinv,
               const int* __restrict__ row_ptr, const int* __restrict__ csr_src,
               const float* __restrict__ b_gcn, float* __restrict__ out) {
  int d = blockIdx.x, t = threadIdx.x;
  if (t >= HIDX / 4) return;
  int c = t * 4;
  float4 acc = {0.f, 0.f, 0.f, 0.f};
  int beg = row_ptr[d], end = row_ptr[d + 1];
  int j = beg;
  for (; j + 3 < end; j += 4) {
    int si0 = csr_src[j],     si1 = csr_src[j + 1];
    int si2 = csr_src[j + 2], si3 = csr_src[j + 3];
    float w0 = dinv[si0], w1 = dinv[si1], w2 = dinv[si2], w3 = dinv[si3];
    uint4 v0 = *(const uint4*)(s + (size_t)si0 * HIDX + c);
    uint4 v1 = *(const uint4*)(s + (size_t)si1 * HIDX + c);
    uint4 v2 = *(const uint4*)(s + (size_t)si2 * HIDX + c);
    uint4 v3 = *(const uint4*)(s + (size_t)si3 * HIDX + c);
    acc.x += w0 * unpackbf(v0.x) + w1 * unpackbf(v1.x) + w2 * unpackbf(v2.x) + w3 * unpackbf(v3.x);
    acc.y += w0 * unpackbf(v0.y) + w1 * unpackbf(v1.y) + w2 * unpackbf(v2.y) + w3 * unpackbf(v3.y);
    acc.z += w0 * unpackbf(v0.z) + w1 * unpackbf(v1.z) + w2 * unpackbf(v2.z) + w3 * unpackbf(v3.z);
    acc.w += w0 * unpackbf(v0.w) + w1 * unpackbf(v1.w) + w2 * unpackbf(v2.w) + w3 * unpackbf(v3.w);
  }
  for (; j < end; j++) {
    int si = csr_src[j];
    float w = dinv[si];
    uint4 sv = *(const uint4*)(s + (size_t)si * HIDX + c);
    acc.x += w * unpackbf(sv.x); acc.y += w * unpackbf(sv.y);
    acc.z += w * unpackbf(sv.z); acc.w += w * unpackbf(sv.w);
  }
  float dd = dinv[d];
  float4 bb = *(const float4*)(b_gcn + c);
  float4 r;
  r.x = fmaxf(acc.x * dd + bb.x, 0.f);
  r.y = fmaxf(acc.y * dd + bb.y, 0.f);
  r.z = fmaxf(acc.z * dd + bb.z, 0.f);
  r.w = fmaxf(acc.w * dd + bb.w, 0.f);
  *(float4*)(out + (size_t)d * HIDX + c) = r;
}

// ---------- per-graph ranges: boundary detection (batch sorted, NO atomics) ----------
__global__ void k_range_init(int* __restrict__ gstart, int* __restrict__ gend) {
  int g = threadIdx.x;
  if (g < N_GRAPHSX) { gstart[g] = 0; gend[g] = 0; }
}
__global__ void k_ranges(const int* __restrict__ batch, int* __restrict__ gstart,
                         int* __restrict__ gend) {
  int n = blockIdx.x * 256 + threadIdx.x;
  if (n >= N_NODESX) return;
  int b = batch[n];
  if (n == 0) {
    gstart[b] = 0;
  } else {
    int pb = batch[n - 1];
    if (pb != b) { gend[pb] = n; gstart[b] = n; }
  }
  if (n == N_NODESX - 1) gend[b] = N_NODESX;
}

// ---------- pooling stage A ----------
__global__ __launch_bounds__(256)
void k_pool_a(const float* __restrict__ xg2, const int* __restrict__ gstart,
              const int* __restrict__ gend,
              float* __restrict__ pmax, float* __restrict__ psum) {
  int g = blockIdx.x, sl = blockIdx.y, t = threadIdx.x;
  if (t >= HIDX / 4) return;
  int c = t * 4;
  int st = gstart[g], en = gend[g];
  int len = en - st; if (len < 0) len = 0;
  int chunk = (len + NSL - 1) / NSL;
  int s0 = st + sl * chunk;
  int s1 = min(en, s0 + chunk);
  float4 mx = {0.f, 0.f, 0.f, 0.f};
  float4 sm = {0.f, 0.f, 0.f, 0.f};
  for (int n = s0; n < s1; n++) {
    float4 v = *(const float4*)(xg2 + (size_t)n * HIDX + c);
    mx.x = fmaxf(mx.x, v.x); sm.x += v.x;
    mx.y = fmaxf(mx.y, v.y); sm.y += v.y;
    mx.z = fmaxf(mx.z, v.z); sm.z += v.z;
    mx.w = fmaxf(mx.w, v.w); sm.w += v.w;
  }
  size_t o = ((size_t)g * NSL + sl) * HIDX + c;
  *(float4*)(pmax + o) = mx;
  *(float4*)(psum + o) = sm;
}

// ---------- pooling stage B ----------
__global__ __launch_bounds__(256)
void k_pool_b(const float* __restrict__ pmax, const float* __restrict__ psum,
              const int* __restrict__ gstart, const int* __restrict__ gend,
              float* __restrict__ xf) {
  int g = blockIdx.x, t = threadIdx.x;
  if (t >= HIDX / 4) return;
  int c = t * 4;
  float4 mx = {0.f, 0.f, 0.f, 0.f};
  float4 sm = {0.f, 0.f, 0.f, 0.f};
  #pragma unroll
  for (int sl = 0; sl < NSL; sl++) {
    size_t o = ((size_t)g * NSL + sl) * HIDX + c;
    float4 m = *(const float4*)(pmax + o);
    float4 s = *(const float4*)(psum + o);
    mx.x = fmaxf(mx.x, m.x); sm.x += s.x;
    mx.y = fmaxf(mx.y, m.y); sm.y += s.y;
    mx.z = fmaxf(mx.z, m.z); sm.z += s.z;
    mx.w = fmaxf(mx.w, m.w); sm.w += s.w;
  }
  int st = gstart[g], en = gend[g];
  float inv = (en > st) ? 1.f / (float)(en - st) : 0.f;
  float* xr = xf + (size_t)g * (2 * HIDX);
  float4 mean; mean.x = sm.x*inv; mean.y = sm.y*inv; mean.z = sm.z*inv; mean.w = sm.w*inv;
  *(float4*)(xr + c) = mx;
  *(float4*)(xr + HIDX + c) = mean;
}

// ---------- label branch ----------
__global__ void k_dvec(const float* __restrict__ A, float* __restrict__ dvec) {
  int i = blockIdx.x * 64 + threadIdx.x;
  if (i >= N_CLASSESX) return;
  float s = 0.f;
  for (int j = 0; j < N_CLASSESX; j++) s += A[i * N_CLASSESX + j];
  dvec[i] = rsqrtf(s);
}
__global__ void k_adj(const float* __restrict__ A, const float* __restrict__ dvec,
                      float* __restrict__ adj) {
  int idx = blockIdx.x * 256 + threadIdx.x;
  if (idx >= N_CLASSESX * N_CLASSESX) return;
  int i = idx / N_CLASSESX, j = idx % N_CLASSESX;
  adj[idx] = dvec[i] * A[j * N_CLASSESX + i] * dvec[j];
}

// ---------- final out = fc2o @ y^T : one wave per output ----------
__global__ __launch_bounds__(256)
void k_out(const float* __restrict__ xf2, const float* __restrict__ y,
           float* __restrict__ out) {
  int gw = (blockIdx.x * 256 + threadIdx.x) >> 6;
  int lane = threadIdx.x & 63;
  if (gw >= N_GRAPHSX * N_CLASSESX) return;
  int b = gw / N_CLASSESX, c = gw - b * N_CLASSESX;
  const float4* xr = (const float4*)(xf2 + (size_t)b * 1024);
  const float4* yr = (const float4*)(y + (size_t)c * 1024);
  float s = 0.f;
  #pragma unroll
  for (int i = 0; i < 4; i++) {
    float4 xv = xr[lane + i * 64], yv = yr[lane + i * 64];
    s += xv.x*yv.x + xv.y*yv.y + xv.z*yv.z + xv.w*yv.w;
  }
  #pragma unroll
  for (int off = 32; off > 0; off >>= 1) s += __shfl_down(s, off, 64);
  if (lane == 0) out[gw] = s;
}

// =======================================================================
extern "C" void kernel_launch(void* const* d_in, const int* in_sizes, int n_in,
                              void* d_out, int out_size, void* d_ws, size_t ws_size,
                              hipStream_t stream) {
  const float* x     = (const float*)d_in[0];
  const int*   ei    = (const int*)d_in[1];
  const int*   batch = (const int*)d_in[2];
  const float* inp   = (const float*)d_in[3];
  const float* W_gat = (const float*)d_in[4];
  const float* a_src = (const float*)d_in[5];
  const float* a_dst = (const float*)d_in[6];
  const float* b_gat = (const float*)d_in[7];
  const float* W_gcn = (const float*)d_in[8];
  const float* b_gcn = (const float*)d_in[9];
  const float* W_fc1 = (const float*)d_in[10];
  const float* b_fc1 = (const float*)d_in[11];
  const float* W_fc2 = (const float*)d_in[12];
  const float* b_fc2 = (const float*)d_in[13];
  const float* W_gc1 = (const float*)d_in[14];
  const float* W_gc2 = (const float*)d_in[15];
  const float* A     = (const float*)d_in[16];
  float* out = (float*)d_out;

  char* ws = (char*)d_ws;
  size_t off = 0;
  auto alloc = [&](size_t bytes) -> void* {
    void* p = ws + off;
    off = (off + bytes + 255) & ~(size_t)255;
    return p;
  };

  // regionA: zh|zl planes [10][M_PAD][KH] (GAT phase), then s packed (GCN phase)
  char* regionA = (char*)alloc((size_t)10 * M_PAD * KH * 2 * 2);
  unsigned short* zh = (unsigned short*)regionA;
  unsigned short* zl = zh + (size_t)10 * M_PAD * KH;
  unsigned* spk = (unsigned*)regionA;                        // 93.6MB <= 115.5MB
  // regionB: xgh|xgl [M_PAD][800] planes, then xg2 fp32 [30000][780]
  char* regionB = (char*)alloc((size_t)M_PAD * KP_GCN * 2 * 2);
  unsigned short* xgh = (unsigned short*)regionB;
  unsigned short* xgl = xgh + (size_t)M_PAD * KP_GCN;
  float* xg2 = (float*)regionB;                              // 93.6MB <= 96.3MB

  float* al_s   = (float*)alloc(sizeof(float) * N_NODESX * HEADSX);
  float* al_d   = (float*)alloc(sizeof(float) * N_NODESX * HEADSX);
  int* counts   = (int*)alloc(sizeof(int) * N_NODESX);
  int* row_ptr  = (int*)alloc(sizeof(int) * (N_NODESX + 1));
  int* cursor   = (int*)alloc(sizeof(int) * N_NODESX);
  int* csr_src  = (int*)alloc(sizeof(int) * N_E);
  float* dinv   = (float*)alloc(sizeof(float) * N_NODESX);
  int* gstart   = (int*)alloc(sizeof(int) * N_GRAPHSX);
  int* gend     = (int*)alloc(sizeof(int) * N_GRAPHSX);
  float* xf     = (float*)alloc(sizeof(float) * N_GRAPHSX * 2 * HIDX);
  float* fc1o   = (float*)alloc(sizeof(float) * N_GRAPHSX * 1500);
  float* fc2o   = (float*)alloc(sizeof(float) * N_GRAPHSX * 1024);
  float* t1     = (float*)alloc(sizeof(float) * N_CLASSESX * 1024);
  float* adj    = (float*)alloc(sizeof(float) * N_CLASSESX * N_CLASSESX);
  float* dvec   = (float*)alloc(sizeof(float) * N_CLASSESX);
  float* y1     = (float*)alloc(sizeof(float) * N_CLASSESX * 1024);
  float* t2     = (float*)alloc(sizeof(float) * N_CLASSESX * 1024);
  float* ybuf   = (float*)alloc(sizeof(float) * N_CLASSESX * 1024);
  float* Ppart  = (float*)alloc(sizeof(float) * 13 * 64 * 1500);
  unsigned short* wcTh = (unsigned short*)alloc(sizeof(short) * (size_t)N_PAD * KP_GCN);
  unsigned short* wcTl = (unsigned short*)alloc(sizeof(short) * (size_t)N_PAD * KP_GCN);
  unsigned short* whTh = (unsigned short*)alloc(sizeof(short) * HEADSX * 128 * KH);
  unsigned short* whTl = (unsigned short*)alloc(sizeof(short) * HEADSX * 128 * KH);
  float* w_as = (float*)alloc(sizeof(float) * HEADSX * F_XDX);
  float* w_ad = (float*)alloc(sizeof(float) * HEADSX * F_XDX);
  // pooling partials alias Ppart (disjoint lifetimes, 3.19MB <= 4.99MB)
  float* pmax = Ppart;
  float* psum = Ppart + (size_t)N_GRAPHSX * NSL * HIDX;
  (void)ws_size; (void)in_sizes; (void)n_in; (void)out_size;

  hipMemsetAsync(counts, 0, sizeof(int) * N_NODESX, stream);
  hipMemsetAsync(cursor, 0, sizeof(int) * N_NODESX, stream);

  // weight prep
  k_splitT<<<(N_PAD * (KP_GCN/8) + 255) / 256, 256, 0, stream>>>(
      W_gcn, HIDX, HIDX, N_PAD, KP_GCN, wcTh, wcTl);
  k_splitT_heads<<<(HEADSX * 128 * (KH/8) + 255) / 256, 256, 0, stream>>>(W_gat, whTh, whTl);
  k_wal<<<(HEADSX * F_XDX + 255) / 256, 256, 0, stream>>>(W_gat, a_src, a_dst, w_as, w_ad);

  // attention logits directly from x (h never materialized)
  k_al2<<<(N_NODESX * HEADSX + 255) / 256, 256, 0, stream>>>(x, w_as, w_ad, al_s, al_d);
  // CSR
  k_count<<<(N_E + 255) / 256, 256, 0, stream>>>(ei, counts);
  k_scan<<<1, 1024, 0, stream>>>(counts, row_ptr);
  k_fill<<<(N_E + 255) / 256, 256, 0, stream>>>(ei, row_ptr, cursor, csr_src);
  // GAT: fused edge-softmax + x-aggregation into z planes, then per-head GEMM
  k_gat_z<<<N_NODESX, 256, 0, stream>>>(x, al_s, al_d, row_ptr, csr_src, zh, zl);
  gemm_head<<<dim3(1, M_PAD / 128, HEADSX), 256, 0, stream>>>(
      zh, zl, whTh, whTl, b_gat, xgh, xgl);
  k_zero_xgpad<<<(M_PAD * 5 + 255) / 256, 256, 0, stream>>>(xgh, xgl);
  // GCN
  k_dinv<<<(N_NODESX + 255) / 256, 256, 0, stream>>>(counts, dinv);
  gemm_mfma3<<<dim3(N_PAD / 128, M_PAD / 128), 256, 0, stream>>>(
      xgh, xgl, wcTh, wcTl, spk, N_NODESX, HIDX, KP_GCN);
  k_gcn_agg<<<N_NODESX, 256, 0, stream>>>(spk, dinv, row_ptr, csr_src, b_gcn, xg2);
  // pooling (2-stage; ranges via boundary detection, no atomics)
  k_range_init<<<1, 64, 0, stream>>>(gstart, gend);
  k_ranges<<<(N_NODESX + 255) / 256, 256, 0, stream>>>(batch, gstart, gend);
  k_pool_a<<<dim3(N_GRAPHSX, NSL), 256, 0, stream>>>(xg2, gstart, gend, pmax, psum);
  k_pool_b<<<N_GRAPHSX, 256, 0, stream>>>(pmax, psum, gstart, gend, xf);

  // ---- dense head via split-K ----
  gemm_sk<<<dim3(24, 1, 13), 256, 0, stream>>>(xf, W_fc1, Ppart, 64, 1500, 1560, 128);
  k_sk_reduce<1, true><<<(64 * 1500 + 255) / 256, 256, 0, stream>>>(
      Ppart, b_fc1, fc1o, 64 * 1500, 1500, 13);
  gemm_sk<<<dim3(16, 1, 12), 256, 0, stream>>>(fc1o, W_fc2, Ppart, 64, 1024, 1500, 128);
  k_sk_reduce<0, true><<<(64 * 1024 + 255) / 256, 256, 0, stream>>>(
      Ppart, b_fc2, fc2o, 64 * 1024, 1024, 12);

  // ---- label branch ----
  k_dvec<<<(N_CLASSESX + 63) / 64, 64, 0, stream>>>(A, dvec);
  k_adj<<<(N_CLASSESX * N_CLASSESX + 255) / 256, 256, 0, stream>>>(A, dvec, adj);
  gemm_sk<<<dim3(16, 2, 5), 256, 0, stream>>>(inp, W_gc1, Ppart, 100, 1024, 300, 64);
  k_sk_reduce<0, false><<<(100 * 1024 + 255) / 256, 256, 0, stream>>>(
      Ppart, nullptr, t1, 100 * 1024, 1024, 5);
  gemm_sk<<<dim3(16, 2, 4), 256, 0, stream>>>(adj, t1, Ppart, 100, 1024, 100, 32);
  k_sk_reduce<2, false><<<(100 * 1024 + 255) / 256, 256, 0, stream>>>(
      Ppart, nullptr, y1, 100 * 1024, 1024, 4);
  gemm_sk<<<dim3(16, 2, 8), 256, 0, stream>>>(y1, W_gc2, Ppart, 100, 1024, 1024, 128);
  k_sk_reduce<0, false><<<(100 * 1024 + 255) / 256, 256, 0, stream>>>(
      Ppart, nullptr, t2, 100 * 1024, 1024, 8);
  gemm_sk<<<dim3(16, 2, 4), 256, 0, stream>>>(adj, t2, Ppart, 100, 1024, 100, 32);
  k_sk_reduce<0, false><<<(100 * 1024 + 255) / 256, 256, 0, stream>>>(
      Ppart, nullptr, ybuf, 100 * 1024, 1024, 4);

  // out = fc2o @ ybuf^T (wave per output)
  k_out<<<(N_GRAPHSX * N_CLASSESX * 64 + 255) / 256, 256, 0, stream>>>(fc2o, ybuf, out);
}